// Round 1
// baseline (1442.881 us; speedup 1.0000x reference)
//
#include <hip/hip_runtime.h>
#include <math.h>

// ---------------------------------------------------------------------------
// Faster-RCNN head pipeline on gfx950.
// Precision strategy: everything that affects NMS *selection* (conv, cls/reg
// heads, scores, boxes, IoU) is computed in fp64 so our ordering matches the
// numpy f64 reference ordering except for true ties (prob ~0). The final FC
// head is fp32 (outputs have generous thresholds / saturated softmax).
// ---------------------------------------------------------------------------

#define H 40
#define W 40
#define CIN 2048
#define CMID 256
#define NBOX 8000   // 40*40*5
#define MAXDET 300

// ---------------------------------------------------------------------------
// Kernel 1: 3x3 SAME conv (2048 -> 256), fp64 accumulation, implicit GEMM.
// Grid: 80 position tiles (half rows of 20) x 16 K-splits (128 in-ch each).
// Block: 256 threads = 256 output channels. 20 positions per thread.
// K-splits combined with fp64 atomicAdd into xsum (zeroed via memset).
// ---------------------------------------------------------------------------
__global__ __launch_bounds__(256) void conv3x3_kernel(
    const float* __restrict__ feat, const float* __restrict__ conv_w,
    double* __restrict__ xsum) {
  __shared__ float flds[3 * 128 * 24];  // [ry][c][col(24, 22 used)] fp32
  const int t = threadIdx.x;
  const int blk = blockIdx.x;
  const int split = blk & 15;        // 16 K-splits
  const int tile = blk >> 4;         // 80 tiles
  const int y = tile >> 1;           // row
  const int xb = (tile & 1) * 20;    // half-row start
  const int c0 = split << 7;         // 128 channels per split

  // Cooperative feature staging: rows y-1..y+1, cols xb-1..xb+20 (22 cols),
  // channels c0..c0+127. Zero padding at borders.
  for (int it = 0; it < 33; ++it) {
    int L = it * 256 + t;
    if (L < 3 * 22 * 128) {
      int c = L & 127;
      int rest = L >> 7;      // 0..65
      int col = rest % 22;
      int ry = rest / 22;
      int gy = y + ry - 1;
      int gx = xb + col - 1;
      float v = 0.f;
      if (gy >= 0 && gy < H && gx >= 0 && gx < W)
        v = feat[(gy * W + gx) * CIN + c0 + c];
      flds[(ry * 128 + c) * 24 + col] = v;
    }
  }
  __syncthreads();

  double acc[20];
#pragma unroll
  for (int p = 0; p < 20; ++p) acc[p] = 0.0;

  for (int ky = 0; ky < 3; ++ky) {
    for (int c = 0; c < 128; ++c) {
      const float* fp = &flds[(ky * 128 + c) * 24];  // 96B aligned
      const float4 f0 = *reinterpret_cast<const float4*>(fp);
      const float4 f1 = *reinterpret_cast<const float4*>(fp + 4);
      const float4 f2 = *reinterpret_cast<const float4*>(fp + 8);
      const float4 f3 = *reinterpret_cast<const float4*>(fp + 12);
      const float4 f4 = *reinterpret_cast<const float4*>(fp + 16);
      const float2 f5 = *reinterpret_cast<const float2*>(fp + 20);
      float fr[22] = {f0.x, f0.y, f0.z, f0.w, f1.x, f1.y, f1.z, f1.w,
                      f2.x, f2.y, f2.z, f2.w, f3.x, f3.y, f3.z, f3.w,
                      f4.x, f4.y, f4.z, f4.w, f5.x, f5.y};
      double fd[22];
#pragma unroll
      for (int q = 0; q < 22; ++q) fd[q] = (double)fr[q];
#pragma unroll
      for (int kx = 0; kx < 3; ++kx) {
        double wd = (double)conv_w[((ky * 3 + kx) * CIN + c0 + c) * CMID + t];
#pragma unroll
        for (int p = 0; p < 20; ++p) acc[p] = fma(wd, fd[p + kx], acc[p]);
      }
    }
  }

  const int pbase = (y * W + xb) * CMID + t;
#pragma unroll
  for (int p = 0; p < 20; ++p) atomicAdd(&xsum[pbase + p * CMID], acc[p]);
}

// ---------------------------------------------------------------------------
// Kernel 2: bias+ReLU, cls (10) + reg (20) 1x1 convs in fp64, sigmoid score,
// anchor box decode. One block per spatial position.
// ---------------------------------------------------------------------------
__global__ __launch_bounds__(256) void heads_kernel(
    const double* __restrict__ xsum, const float* __restrict__ conv_b,
    const float* __restrict__ cls_w, const float* __restrict__ cls_b,
    const float* __restrict__ reg_w, const float* __restrict__ reg_b,
    double* __restrict__ scores, double* __restrict__ boxes) {
  __shared__ double xd[256];
  __shared__ double outv[32];
  const int p = blockIdx.x;
  const int t = threadIdx.x;
  double v = xsum[p * 256 + t] + (double)conv_b[t];
  xd[t] = v > 0.0 ? v : 0.0;
  __syncthreads();

  const int wave = t >> 6, lane = t & 63;
  for (int q = 0; q < 8; ++q) {
    int o = wave * 8 + q;
    if (o < 30) {  // uniform within wave
      double acc = 0.0;
      if (o < 10) {
#pragma unroll
        for (int k = 0; k < 4; ++k)
          acc += xd[lane * 4 + k] * (double)cls_w[(lane * 4 + k) * 10 + o];
      } else {
        int oo = o - 10;
#pragma unroll
        for (int k = 0; k < 4; ++k)
          acc += xd[lane * 4 + k] * (double)reg_w[(lane * 4 + k) * 20 + oo];
      }
#pragma unroll
      for (int off = 32; off > 0; off >>= 1) acc += __shfl_down(acc, off);
      if (lane == 0) outv[o] = acc;
    }
  }
  __syncthreads();

  if (t < 5) {
    const int a = t;
    double l0 = outv[2 * a] + (double)cls_b[2 * a];
    double l1 = outv[2 * a + 1] + (double)cls_b[2 * a + 1];
    double sc = 1.0 / (1.0 + exp(l0 - l1));  // == softmax[...,1]
    const int n = p * 5 + a;
    scores[n] = sc;
    double d0 = outv[10 + 4 * a + 0] + (double)reg_b[4 * a + 0];
    double d1 = outv[10 + 4 * a + 1] + (double)reg_b[4 * a + 1];
    double d2 = outv[10 + 4 * a + 2] + (double)reg_b[4 * a + 2];
    double d3 = outv[10 + 4 * a + 3] + (double)reg_b[4 * a + 3];
    double scale = (double)(32 << a);  // 32,64,128,256,512 (ratio=1)
    double wdt = exp(d2) * scale;
    double hgt = exp(d3) * scale;
    double xc = (double)(p % W) + d0;  // FEATURE_STRIDE = 1
    double yc = (double)(p / W) + d1;
    boxes[n * 4 + 0] = xc - 0.5 * wdt;
    boxes[n * 4 + 1] = yc - 0.5 * hgt;
    boxes[n * 4 + 2] = xc + 0.5 * wdt;
    boxes[n * 4 + 3] = yc + 0.5 * hgt;
  }
}

// ---------------------------------------------------------------------------
// Kernel 3: exact stable descending argsort via O(N^2) rank counting.
// rank(i) = #{ j : s_j > s_i  or (s_j == s_i and j < i) }  -> unique ranks.
// Scatters boxes+area into sorted order. Grid 32 x 256.
// ---------------------------------------------------------------------------
__global__ __launch_bounds__(256) void rank_kernel(
    const double* __restrict__ scores, const double* __restrict__ boxes,
    double* __restrict__ bs, double* __restrict__ area) {
  __shared__ double sch[1024];
  const int t = threadIdx.x;
  const int i = blockIdx.x * 256 + t;
  const bool act = i < NBOX;
  const double si = act ? scores[i] : 0.0;
  int cnt = 0;
  for (int base = 0; base < NBOX; base += 1024) {
    const int lim = min(1024, NBOX - base);  // always even
    __syncthreads();
#pragma unroll
    for (int q = 0; q < 4; ++q) {
      int j = base + t * 4 + q;
      sch[t * 4 + q] = (j < NBOX) ? scores[j] : -1.0;
    }
    __syncthreads();
    for (int jj = 0; jj < lim; jj += 2) {
      double a0 = sch[jj], a1 = sch[jj + 1];
      int j0 = base + jj;
      cnt += (a0 > si || (a0 == si && j0 < i)) ? 1 : 0;
      cnt += (a1 > si || (a1 == si && (j0 + 1) < i)) ? 1 : 0;
    }
  }
  if (act) {
    double b0 = boxes[i * 4 + 0], b1 = boxes[i * 4 + 1];
    double b2 = boxes[i * 4 + 2], b3 = boxes[i * 4 + 3];
    bs[cnt * 4 + 0] = b0;
    bs[cnt * 4 + 1] = b1;
    bs[cnt * 4 + 2] = b2;
    bs[cnt * 4 + 3] = b3;
    area[cnt] = (b2 - b0) * (b3 - b1);
  }
}

// ---------------------------------------------------------------------------
// Kernel 4: greedy NMS (iou >= 0.7) on sorted boxes, single 1024-thread block.
// Ballot-accelerated scan for next kept index; fp64 IoU; then block prefix
// sum -> first 300 rois written directly into d_out (+2400). Invalid rows = 0.
// ---------------------------------------------------------------------------
__global__ __launch_bounds__(1024) void nms_kernel(
    const double* __restrict__ bs, const double* __restrict__ area,
    float* __restrict__ rois_out) {
  __shared__ unsigned char keep[NBOX];
  __shared__ int counts[1024];
  __shared__ int selK[MAXDET];
  __shared__ int nk_sh;
  const int t = threadIdx.x;
  const int lane = t & 63;

  for (int q = t; q < NBOX; q += 1024) keep[q] = 1;
  __syncthreads();

  int i = 0;
  while (i < NBOX) {
    // All waves scan identically (reads only; last writes were pre-barrier).
    int found = -1;
    int base = i;
    while (base < NBOX) {
      int idx = base + lane;
      bool k = (idx < NBOX) && keep[idx];
      unsigned long long m = __ballot(k ? 1 : 0);
      if (m) { found = base + (__ffsll(m) - 1); break; }
      base += 64;
    }
    if (found < 0) break;
    i = found;
    __syncthreads();  // all waves agree on i before any suppression writes

    const double x1 = bs[i * 4 + 0], y1 = bs[i * 4 + 1];
    const double x2 = bs[i * 4 + 2], y2 = bs[i * 4 + 3];
    const double ai = area[i];
    for (int j = i + 1 + t; j < NBOX; j += 1024) {
      if (!keep[j]) continue;  // skip dead -> avoids most global loads
      double bx1 = bs[j * 4 + 0], by1 = bs[j * 4 + 1];
      double bx2 = bs[j * 4 + 2], by2 = bs[j * 4 + 3];
      double iw = fmin(x2, bx2) - fmax(x1, bx1);
      iw = iw > 0.0 ? iw : 0.0;
      double ih = fmin(y2, by2) - fmax(y1, by1);
      ih = ih > 0.0 ? ih : 0.0;
      double inter = iw * ih;
      double iou = inter / (ai + area[j] - inter);
      if (iou >= 0.7) keep[j] = 0;
    }
    __syncthreads();
    ++i;
  }
  __syncthreads();

  // Prefix sum over keep -> selK (kept indices in sorted order).
  int cnt = 0;
  const int p0 = t * 8;
#pragma unroll
  for (int q = 0; q < 8; ++q) {
    int p = p0 + q;
    if (p < NBOX && keep[p]) cnt++;
  }
  counts[t] = cnt;
  __syncthreads();
  if (t == 0) {
    int run = 0;
    for (int b = 0; b < 1024; ++b) {
      int c = counts[b];
      counts[b] = run;
      run += c;
    }
    nk_sh = run;
  }
  __syncthreads();
  int rk = counts[t];
#pragma unroll
  for (int q = 0; q < 8; ++q) {
    int p = p0 + q;
    if (p < NBOX && keep[p]) {
      if (rk < MAXDET) selK[rk] = p;
      rk++;
    }
  }
  __syncthreads();

  int nk = nk_sh;
  if (nk > MAXDET) nk = MAXDET;
  for (int r = t; r < MAXDET; r += 1024) {
    if (r < nk) {
      int p = selK[r];
      rois_out[r * 4 + 0] = (float)bs[p * 4 + 0];
      rois_out[r * 4 + 1] = (float)bs[p * 4 + 1];
      rois_out[r * 4 + 2] = (float)bs[p * 4 + 2];
      rois_out[r * 4 + 3] = (float)bs[p * 4 + 3];
    } else {  // rois = b[sel] * 0 exactly
      rois_out[r * 4 + 0] = 0.f;
      rois_out[r * 4 + 1] = 0.f;
      rois_out[r * 4 + 2] = 0.f;
      rois_out[r * 4 + 3] = 0.f;
    }
  }
}

// ---------------------------------------------------------------------------
// Kernel 5: FC head. fc = relu(roi @ fc1_w + fc1_b) (1024), then
// class_scores = softmax(fc @ clsh_w + clsh_b), box_deltas = fc @ regh_w + b.
// One block per roi. fp32 (tolerances generous; softmax saturated).
// Invalid rows (roi==0, biases zero) give 0.25/0 automatically, matching ref.
// ---------------------------------------------------------------------------
__global__ __launch_bounds__(256) void rcnn_head_kernel(
    const float* __restrict__ rois, const float* __restrict__ fc1_w,
    const float* __restrict__ fc1_b, const float* __restrict__ clsh_w,
    const float* __restrict__ clsh_b, const float* __restrict__ regh_w,
    const float* __restrict__ regh_b, float* __restrict__ out) {
  __shared__ float red[256 * 8];
  const int r = blockIdx.x, t = threadIdx.x;
  const float r0 = rois[r * 4 + 0], r1 = rois[r * 4 + 1];
  const float r2 = rois[r * 4 + 2], r3 = rois[r * 4 + 3];
  float pc[4] = {0, 0, 0, 0}, pb[4] = {0, 0, 0, 0};
#pragma unroll
  for (int q = 0; q < 4; ++q) {
    int j = t * 4 + q;
    float f = r0 * fc1_w[j] + r1 * fc1_w[1024 + j] + r2 * fc1_w[2048 + j] +
              r3 * fc1_w[3072 + j] + fc1_b[j];
    f = fmaxf(f, 0.f);
#pragma unroll
    for (int c = 0; c < 4; ++c) {
      pc[c] += f * clsh_w[j * 4 + c];
      pb[c] += f * regh_w[j * 4 + c];
    }
  }
#pragma unroll
  for (int u = 0; u < 4; ++u) {
    red[t * 8 + u] = pc[u];
    red[t * 8 + 4 + u] = pb[u];
  }
  __syncthreads();
  for (int s = 128; s > 0; s >>= 1) {
    if (t < s) {
#pragma unroll
      for (int u = 0; u < 8; ++u) red[t * 8 + u] += red[(t + s) * 8 + u];
    }
    __syncthreads();
  }
  if (t == 0) {
    float lg[4];
    float m = -1e30f;
#pragma unroll
    for (int c = 0; c < 4; ++c) {
      lg[c] = red[c] + clsh_b[c];
      m = fmaxf(m, lg[c]);
    }
    float s = 0.f;
#pragma unroll
    for (int c = 0; c < 4; ++c) {
      lg[c] = expf(lg[c] - m);
      s += lg[c];
    }
#pragma unroll
    for (int c = 0; c < 4; ++c) out[r * 4 + c] = lg[c] / s;
#pragma unroll
    for (int k = 0; k < 4; ++k)
      out[1200 + r * 4 + k] = red[4 + k] + regh_b[k];
  }
}

// ---------------------------------------------------------------------------
extern "C" void kernel_launch(void* const* d_in, const int* in_sizes, int n_in,
                              void* d_out, int out_size, void* d_ws,
                              size_t ws_size, hipStream_t stream) {
  const float* feat = (const float*)d_in[0];
  const float* conv_w = (const float*)d_in[1];
  const float* conv_b = (const float*)d_in[2];
  const float* cls_w = (const float*)d_in[3];
  const float* cls_b = (const float*)d_in[4];
  const float* reg_w = (const float*)d_in[5];
  const float* reg_b = (const float*)d_in[6];
  const float* fc1_w = (const float*)d_in[7];
  const float* fc1_b = (const float*)d_in[8];
  const float* clsh_w = (const float*)d_in[9];
  const float* clsh_b = (const float*)d_in[10];
  const float* regh_w = (const float*)d_in[11];
  const float* regh_b = (const float*)d_in[12];
  float* out = (float*)d_out;

  char* w = (char*)d_ws;
  double* xsum = (double*)(w);                 // 1600*256*8   = 3,276,800 B
  double* scores = (double*)(w + 3276800);     // 8000*8       =    64,000 B
  double* boxes = (double*)(w + 3340800);      // 8000*4*8     =   256,000 B
  double* bs = (double*)(w + 3596800);         // 8000*4*8     =   256,000 B
  double* area = (double*)(w + 3852800);       // 8000*8       =    64,000 B

  hipMemsetAsync(xsum, 0, 3276800, stream);
  conv3x3_kernel<<<1280, 256, 0, stream>>>(feat, conv_w, xsum);
  heads_kernel<<<1600, 256, 0, stream>>>(xsum, conv_b, cls_w, cls_b, reg_w,
                                         reg_b, scores, boxes);
  rank_kernel<<<32, 256, 0, stream>>>(scores, boxes, bs, area);
  nms_kernel<<<1, 1024, 0, stream>>>(bs, area, out + 2400);
  rcnn_head_kernel<<<300, 256, 0, stream>>>(out + 2400, fc1_w, fc1_b, clsh_w,
                                            clsh_b, regh_w, regh_b, out);
}

// Round 2
// 966.760 us; speedup vs baseline: 1.4925x; 1.4925x over previous
//
#include <hip/hip_runtime.h>
#include <math.h>

// ---------------------------------------------------------------------------
// Faster-RCNN head pipeline on gfx950.
// Precision strategy: everything that affects NMS *selection* (conv, cls/reg
// heads, scores, boxes, IoU) is computed in fp64 so our ordering matches the
// numpy f64 reference ordering except for true ties (prob ~0). The final FC
// head is fp32 (outputs have generous thresholds / saturated softmax).
//
// R1: NMS overhauled. Old single-block greedy NMS was 762 us (53%) —
// latency-bound serial loop on 1 CU. Replaced by:
//   (a) iou_matrix_kernel: 8000x8000 suppression bit-matrix, massively
//       parallel fp64 (div-free: inter >= 0.7*union, identical decision).
//   (b) nms_serial_kernel: 1 wave, 125 chunk iterations; per chunk ONE
//       parallel 64-lane gather of diagonal row-words, then in-register
//       shfl-based serial resolution; row ORs into a 125-word LDS mask.
//       Early-exit at 300 kept (suppression only flows forward).
// ---------------------------------------------------------------------------

#define H 40
#define W 40
#define CIN 2048
#define CMID 256
#define NBOX 8000   // 40*40*5
#define NCH 125     // NBOX / 64 chunks
#define ROWW 128    // padded row width (ullong words) of suppression matrix
#define MAXDET 300

// ---------------------------------------------------------------------------
// Kernel 1: 3x3 SAME conv (2048 -> 256), fp64 accumulation, implicit GEMM.
// ---------------------------------------------------------------------------
__global__ __launch_bounds__(256) void conv3x3_kernel(
    const float* __restrict__ feat, const float* __restrict__ conv_w,
    double* __restrict__ xsum) {
  __shared__ float flds[3 * 128 * 24];  // [ry][c][col(24, 22 used)] fp32
  const int t = threadIdx.x;
  const int blk = blockIdx.x;
  const int split = blk & 15;        // 16 K-splits
  const int tile = blk >> 4;         // 80 tiles
  const int y = tile >> 1;           // row
  const int xb = (tile & 1) * 20;    // half-row start
  const int c0 = split << 7;         // 128 channels per split

  for (int it = 0; it < 33; ++it) {
    int L = it * 256 + t;
    if (L < 3 * 22 * 128) {
      int c = L & 127;
      int rest = L >> 7;      // 0..65
      int col = rest % 22;
      int ry = rest / 22;
      int gy = y + ry - 1;
      int gx = xb + col - 1;
      float v = 0.f;
      if (gy >= 0 && gy < H && gx >= 0 && gx < W)
        v = feat[(gy * W + gx) * CIN + c0 + c];
      flds[(ry * 128 + c) * 24 + col] = v;
    }
  }
  __syncthreads();

  double acc[20];
#pragma unroll
  for (int p = 0; p < 20; ++p) acc[p] = 0.0;

  for (int ky = 0; ky < 3; ++ky) {
    for (int c = 0; c < 128; ++c) {
      const float* fp = &flds[(ky * 128 + c) * 24];  // 96B aligned
      const float4 f0 = *reinterpret_cast<const float4*>(fp);
      const float4 f1 = *reinterpret_cast<const float4*>(fp + 4);
      const float4 f2 = *reinterpret_cast<const float4*>(fp + 8);
      const float4 f3 = *reinterpret_cast<const float4*>(fp + 12);
      const float4 f4 = *reinterpret_cast<const float4*>(fp + 16);
      const float2 f5 = *reinterpret_cast<const float2*>(fp + 20);
      float fr[22] = {f0.x, f0.y, f0.z, f0.w, f1.x, f1.y, f1.z, f1.w,
                      f2.x, f2.y, f2.z, f2.w, f3.x, f3.y, f3.z, f3.w,
                      f4.x, f4.y, f4.z, f4.w, f5.x, f5.y};
      double fd[22];
#pragma unroll
      for (int q = 0; q < 22; ++q) fd[q] = (double)fr[q];
#pragma unroll
      for (int kx = 0; kx < 3; ++kx) {
        double wd = (double)conv_w[((ky * 3 + kx) * CIN + c0 + c) * CMID + t];
#pragma unroll
        for (int p = 0; p < 20; ++p) acc[p] = fma(wd, fd[p + kx], acc[p]);
      }
    }
  }

  const int pbase = (y * W + xb) * CMID + t;
#pragma unroll
  for (int p = 0; p < 20; ++p) atomicAdd(&xsum[pbase + p * CMID], acc[p]);
}

// ---------------------------------------------------------------------------
// Kernel 2: bias+ReLU, cls (10) + reg (20) 1x1 convs in fp64, sigmoid score,
// anchor box decode. One block per spatial position.
// ---------------------------------------------------------------------------
__global__ __launch_bounds__(256) void heads_kernel(
    const double* __restrict__ xsum, const float* __restrict__ conv_b,
    const float* __restrict__ cls_w, const float* __restrict__ cls_b,
    const float* __restrict__ reg_w, const float* __restrict__ reg_b,
    double* __restrict__ scores, double* __restrict__ boxes) {
  __shared__ double xd[256];
  __shared__ double outv[32];
  const int p = blockIdx.x;
  const int t = threadIdx.x;
  double v = xsum[p * 256 + t] + (double)conv_b[t];
  xd[t] = v > 0.0 ? v : 0.0;
  __syncthreads();

  const int wave = t >> 6, lane = t & 63;
  for (int q = 0; q < 8; ++q) {
    int o = wave * 8 + q;
    if (o < 30) {  // uniform within wave
      double acc = 0.0;
      if (o < 10) {
#pragma unroll
        for (int k = 0; k < 4; ++k)
          acc += xd[lane * 4 + k] * (double)cls_w[(lane * 4 + k) * 10 + o];
      } else {
        int oo = o - 10;
#pragma unroll
        for (int k = 0; k < 4; ++k)
          acc += xd[lane * 4 + k] * (double)reg_w[(lane * 4 + k) * 20 + oo];
      }
#pragma unroll
      for (int off = 32; off > 0; off >>= 1) acc += __shfl_down(acc, off);
      if (lane == 0) outv[o] = acc;
    }
  }
  __syncthreads();

  if (t < 5) {
    const int a = t;
    double l0 = outv[2 * a] + (double)cls_b[2 * a];
    double l1 = outv[2 * a + 1] + (double)cls_b[2 * a + 1];
    double sc = 1.0 / (1.0 + exp(l0 - l1));  // == softmax[...,1]
    const int n = p * 5 + a;
    scores[n] = sc;
    double d0 = outv[10 + 4 * a + 0] + (double)reg_b[4 * a + 0];
    double d1 = outv[10 + 4 * a + 1] + (double)reg_b[4 * a + 1];
    double d2 = outv[10 + 4 * a + 2] + (double)reg_b[4 * a + 2];
    double d3 = outv[10 + 4 * a + 3] + (double)reg_b[4 * a + 3];
    double scale = (double)(32 << a);  // 32,64,128,256,512 (ratio=1)
    double wdt = exp(d2) * scale;
    double hgt = exp(d3) * scale;
    double xc = (double)(p % W) + d0;  // FEATURE_STRIDE = 1
    double yc = (double)(p / W) + d1;
    boxes[n * 4 + 0] = xc - 0.5 * wdt;
    boxes[n * 4 + 1] = yc - 0.5 * hgt;
    boxes[n * 4 + 2] = xc + 0.5 * wdt;
    boxes[n * 4 + 3] = yc + 0.5 * hgt;
  }
}

// ---------------------------------------------------------------------------
// Kernel 3: exact stable descending argsort via O(N^2) rank counting.
// ---------------------------------------------------------------------------
__global__ __launch_bounds__(256) void rank_kernel(
    const double* __restrict__ scores, const double* __restrict__ boxes,
    double* __restrict__ bs, double* __restrict__ area) {
  __shared__ double sch[1024];
  const int t = threadIdx.x;
  const int i = blockIdx.x * 256 + t;
  const bool act = i < NBOX;
  const double si = act ? scores[i] : 0.0;
  int cnt = 0;
  for (int base = 0; base < NBOX; base += 1024) {
    const int lim = min(1024, NBOX - base);
    __syncthreads();
#pragma unroll
    for (int q = 0; q < 4; ++q) {
      int j = base + t * 4 + q;
      sch[t * 4 + q] = (j < NBOX) ? scores[j] : -1.0;
    }
    __syncthreads();
    for (int jj = 0; jj < lim; jj += 2) {
      double a0 = sch[jj], a1 = sch[jj + 1];
      int j0 = base + jj;
      cnt += (a0 > si || (a0 == si && j0 < i)) ? 1 : 0;
      cnt += (a1 > si || (a1 == si && (j0 + 1) < i)) ? 1 : 0;
    }
  }
  if (act) {
    double b0 = boxes[i * 4 + 0], b1 = boxes[i * 4 + 1];
    double b2 = boxes[i * 4 + 2], b3 = boxes[i * 4 + 3];
    bs[cnt * 4 + 0] = b0;
    bs[cnt * 4 + 1] = b1;
    bs[cnt * 4 + 2] = b2;
    bs[cnt * 4 + 3] = b3;
    area[cnt] = (b2 - b0) * (b3 - b1);
  }
}

// ---------------------------------------------------------------------------
// Kernel 4a: suppression bit-matrix. Row i, word tj: bit l set iff
// j = tj*64+l has j>i and iou(i,j) >= 0.7. Div-free compare:
// inter >= 0.7*(ai+aj-inter)  (union always > 0; identical decision to
// within ~1e-16 relative rounding — negligible flip probability).
// Grid: 125*125 tiles of 64(i) x 64(j); block 256 = 4 waves x 16 i each.
// ---------------------------------------------------------------------------
__global__ __launch_bounds__(256) void iou_matrix_kernel(
    const double* __restrict__ bs, const double* __restrict__ area,
    unsigned long long* __restrict__ supmat) {
  __shared__ double jx1[64], jy1[64], jx2[64], jy2[64], ja[64];
  __shared__ double ix1[64], iy1[64], ix2[64], iy2[64], ia[64];
  const int ti = blockIdx.x / NCH, tj = blockIdx.x % NCH;
  const int t = threadIdx.x, wv = t >> 6, lane = t & 63;
  if (t < 64) {
    int j = tj * 64 + t;
    jx1[t] = bs[j * 4 + 0];
    jy1[t] = bs[j * 4 + 1];
    jx2[t] = bs[j * 4 + 2];
    jy2[t] = bs[j * 4 + 3];
    ja[t] = area[j];
  } else if (t < 128) {
    int l = t - 64;
    int i = ti * 64 + l;
    ix1[l] = bs[i * 4 + 0];
    iy1[l] = bs[i * 4 + 1];
    ix2[l] = bs[i * 4 + 2];
    iy2[l] = bs[i * 4 + 3];
    ia[l] = area[i];
  }
  __syncthreads();
  const double x1 = jx1[lane], y1 = jy1[lane], x2 = jx2[lane], y2 = jy2[lane];
  const double aj = ja[lane];
  const int jglob = tj * 64 + lane;
#pragma unroll 4
  for (int s = 0; s < 16; ++s) {
    const int il = wv * 16 + s;
    const int i = ti * 64 + il;
    const double bx1 = ix1[il], by1 = iy1[il], bx2 = ix2[il], by2 = iy2[il];
    const double ai = ia[il];
    double iw = fmin(x2, bx2) - fmax(x1, bx1);
    iw = iw > 0.0 ? iw : 0.0;
    double ih = fmin(y2, by2) - fmax(y1, by1);
    ih = ih > 0.0 ? ih : 0.0;
    double inter = iw * ih;
    bool sup = (jglob > i) && (inter >= 0.7 * (ai + aj - inter));
    unsigned long long wmask = __ballot(sup ? 1 : 0);
    if (lane == 0) supmat[(size_t)i * ROWW + tj] = wmask;
  }
}

// ---------------------------------------------------------------------------
// Kernel 4b: serial greedy resolution over the bit-matrix. ONE wave.
// Per 64-box chunk: one parallel gather of the chunk's diagonal row-words
// (lane l holds row(tc*64+l)[tc]), then a uniform in-register serial loop:
// lowest unsuppressed bit -> kept -> OR its (shfl-broadcast) word into the
// chunk suppression word. Kept rows' remaining words OR into LDS mask for
// future chunks. Early-exit at 300 kept. Writes rois directly.
// ---------------------------------------------------------------------------
__global__ __launch_bounds__(64) void nms_serial_kernel(
    const double* __restrict__ bs,
    const unsigned long long* __restrict__ supmat,
    float* __restrict__ rois_out) {
  __shared__ unsigned long long mask[NCH];
  __shared__ int selK[MAXDET];
  const int lane = threadIdx.x;

  mask[lane] = 0ull;
  if (lane + 64 < NCH) mask[lane + 64] = 0ull;
  __syncthreads();

  int nk = 0;
  // prefetch chunk 0 diagonal words
  unsigned long long wdiag = supmat[(size_t)lane * ROWW + 0];

  for (int tc = 0; tc < NCH && nk < MAXDET; ++tc) {
    unsigned long long m = mask[tc];   // broadcast LDS read (uniform)
    unsigned long long wcur = wdiag;
    // prefetch next chunk's diagonal words (overlaps with serial phase)
    unsigned long long wnext = 0ull;
    if (tc + 1 < NCH)
      wnext = supmat[(size_t)((tc + 1) * 64 + lane) * ROWW + (tc + 1)];

    unsigned long long cand = ~m;      // all 64 boxes valid (8000 = 125*64)
    unsigned long long keptbits = 0ull;
    while (cand && nk < MAXDET) {      // fully uniform loop
      int b = __ffsll(cand) - 1;       // lowest-ranked unsuppressed candidate
      unsigned long long bit = 1ull << b;
      keptbits |= bit;
      if (lane == 0) selK[nk] = tc * 64 + b;
      nk++;
      unsigned long long row = __shfl(wcur, b);  // its in-chunk suppressions
      cand &= ~(row | bit);
    }
    // propagate kept rows into future mask words (parallel over lanes)
    unsigned long long kb = keptbits;
    while (kb) {
      int b = __ffsll(kb) - 1;
      kb &= kb - 1;
      const size_t rbase = (size_t)(tc * 64 + b) * ROWW;
      for (int w = tc + 1 + lane; w < NCH; w += 64)
        mask[w] |= supmat[rbase + w];
    }
    wdiag = wnext;
    __syncthreads();  // mask writes visible before next chunk's read
  }
  __syncthreads();

  const int NK = nk;  // uniform
  for (int r = lane; r < MAXDET; r += 64) {
    if (r < NK) {
      int p = selK[r];
      rois_out[r * 4 + 0] = (float)bs[p * 4 + 0];
      rois_out[r * 4 + 1] = (float)bs[p * 4 + 1];
      rois_out[r * 4 + 2] = (float)bs[p * 4 + 2];
      rois_out[r * 4 + 3] = (float)bs[p * 4 + 3];
    } else {  // rois = b[sel] * 0 exactly
      rois_out[r * 4 + 0] = 0.f;
      rois_out[r * 4 + 1] = 0.f;
      rois_out[r * 4 + 2] = 0.f;
      rois_out[r * 4 + 3] = 0.f;
    }
  }
}

// ---------------------------------------------------------------------------
// Kernel 5: FC head (fp32; tolerances generous, softmax saturated).
// ---------------------------------------------------------------------------
__global__ __launch_bounds__(256) void rcnn_head_kernel(
    const float* __restrict__ rois, const float* __restrict__ fc1_w,
    const float* __restrict__ fc1_b, const float* __restrict__ clsh_w,
    const float* __restrict__ clsh_b, const float* __restrict__ regh_w,
    const float* __restrict__ regh_b, float* __restrict__ out) {
  __shared__ float red[256 * 8];
  const int r = blockIdx.x, t = threadIdx.x;
  const float r0 = rois[r * 4 + 0], r1 = rois[r * 4 + 1];
  const float r2 = rois[r * 4 + 2], r3 = rois[r * 4 + 3];
  float pc[4] = {0, 0, 0, 0}, pb[4] = {0, 0, 0, 0};
#pragma unroll
  for (int q = 0; q < 4; ++q) {
    int j = t * 4 + q;
    float f = r0 * fc1_w[j] + r1 * fc1_w[1024 + j] + r2 * fc1_w[2048 + j] +
              r3 * fc1_w[3072 + j] + fc1_b[j];
    f = fmaxf(f, 0.f);
#pragma unroll
    for (int c = 0; c < 4; ++c) {
      pc[c] += f * clsh_w[j * 4 + c];
      pb[c] += f * regh_w[j * 4 + c];
    }
  }
#pragma unroll
  for (int u = 0; u < 4; ++u) {
    red[t * 8 + u] = pc[u];
    red[t * 8 + 4 + u] = pb[u];
  }
  __syncthreads();
  for (int s = 128; s > 0; s >>= 1) {
    if (t < s) {
#pragma unroll
      for (int u = 0; u < 8; ++u) red[t * 8 + u] += red[(t + s) * 8 + u];
    }
    __syncthreads();
  }
  if (t == 0) {
    float lg[4];
    float m = -1e30f;
#pragma unroll
    for (int c = 0; c < 4; ++c) {
      lg[c] = red[c] + clsh_b[c];
      m = fmaxf(m, lg[c]);
    }
    float s = 0.f;
#pragma unroll
    for (int c = 0; c < 4; ++c) {
      lg[c] = expf(lg[c] - m);
      s += lg[c];
    }
#pragma unroll
    for (int c = 0; c < 4; ++c) out[r * 4 + c] = lg[c] / s;
#pragma unroll
    for (int k = 0; k < 4; ++k)
      out[1200 + r * 4 + k] = red[4 + k] + regh_b[k];
  }
}

// ---------------------------------------------------------------------------
extern "C" void kernel_launch(void* const* d_in, const int* in_sizes, int n_in,
                              void* d_out, int out_size, void* d_ws,
                              size_t ws_size, hipStream_t stream) {
  const float* feat = (const float*)d_in[0];
  const float* conv_w = (const float*)d_in[1];
  const float* conv_b = (const float*)d_in[2];
  const float* cls_w = (const float*)d_in[3];
  const float* cls_b = (const float*)d_in[4];
  const float* reg_w = (const float*)d_in[5];
  const float* reg_b = (const float*)d_in[6];
  const float* fc1_w = (const float*)d_in[7];
  const float* fc1_b = (const float*)d_in[8];
  const float* clsh_w = (const float*)d_in[9];
  const float* clsh_b = (const float*)d_in[10];
  const float* regh_w = (const float*)d_in[11];
  const float* regh_b = (const float*)d_in[12];
  float* out = (float*)d_out;

  char* w = (char*)d_ws;
  double* xsum = (double*)(w);                 // 1600*256*8   = 3,276,800 B
  double* scores = (double*)(w + 3276800);     // 8000*8       =    64,000 B
  double* boxes = (double*)(w + 3340800);      // 8000*4*8     =   256,000 B
  double* bs = (double*)(w + 3596800);         // 8000*4*8     =   256,000 B
  double* area = (double*)(w + 3852800);       // 8000*8       =    64,000 B
  unsigned long long* supmat =
      (unsigned long long*)(w + 3916800);      // 8000*128*8   = 8,192,000 B

  hipMemsetAsync(xsum, 0, 3276800, stream);
  conv3x3_kernel<<<1280, 256, 0, stream>>>(feat, conv_w, xsum);
  heads_kernel<<<1600, 256, 0, stream>>>(xsum, conv_b, cls_w, cls_b, reg_w,
                                         reg_b, scores, boxes);
  rank_kernel<<<32, 256, 0, stream>>>(scores, boxes, bs, area);
  iou_matrix_kernel<<<NCH * NCH, 256, 0, stream>>>(bs, area, supmat);
  nms_serial_kernel<<<1, 64, 0, stream>>>(bs, supmat, out + 2400);
  rcnn_head_kernel<<<300, 256, 0, stream>>>(out + 2400, fc1_w, fc1_b, clsh_w,
                                            clsh_b, regh_w, regh_b, out);
}

// Round 4
// 893.018 us; speedup vs baseline: 1.6157x; 1.0826x over previous
//
#include <hip/hip_runtime.h>
#include <math.h>

// ---------------------------------------------------------------------------
// Faster-RCNN head pipeline on gfx950.
// Precision strategy: everything that affects NMS *selection* (conv, cls/reg
// heads, scores, boxes, IoU) is computed in fp64 so our ordering matches the
// numpy f64 reference ordering except for true ties (prob ~0). The final FC
// head is fp32 (outputs have generous thresholds / saturated softmax).
//
// R1: NMS 762us -> iou bit-matrix (parallel) + 1-wave serial resolution.
// R2: conv3x3 -> v_mfma_f64_16x16x4 implicit GEMM. FAILED (abs 53): f64 C/D
//     register layout is NOT covered by the verified dtype-independence cells.
// R3: self-calibrating epilogue — two probe MFMAs discover the true per-
//     (lane,reg) -> (row,col) D mapping at runtime; scatter uses it. Robust
//     to ANY C/D layout (D is always a 256-element bijection).
// ---------------------------------------------------------------------------

#define H 40
#define W 40
#define CIN 2048
#define CMID 256
#define NBOX 8000   // 40*40*5
#define NCH 125     // NBOX / 64 chunks
#define ROWW 128    // padded row width (ullong words) of suppression matrix
#define MAXDET 300

typedef double d4 __attribute__((ext_vector_type(4)));

// ---------------------------------------------------------------------------
// Kernel 1: 3x3 SAME conv (2048 -> 256) via v_mfma_f64_16x16x4.
// Grid 1280 = 20 M-tiles (2 rows, 80 pos) x 64 K-splits (32 ch each).
// Block 512 = 8 waves; wave w owns outch [w*32, w*32+32) = 2 N-frags.
// Operand feeding (universal 16-lane-group structure):
//   A[m][k]: m=lane&15, k=lane>>4;  B[k][n]: n=lane&15, k=lane>>4.
// D mapping: discovered at runtime via probe MFMAs (f64 layout unverified).
// ---------------------------------------------------------------------------
__global__ __launch_bounds__(512, 2) void conv3x3_kernel(
    const float* __restrict__ feat, const float* __restrict__ conv_w,
    double* __restrict__ xsum) {
  __shared__ double patch[4][42][33];  // rows y0-1..y0+2, cols -1..40, 32ch+pad
  const int t = threadIdx.x;
  const int s = blockIdx.x & 63;   // K-split: channels c0..c0+31
  const int mt = blockIdx.x >> 6;  // M-tile: rows y0, y0+1
  const int y0 = mt * 2;
  const int c0 = s * 32;

  // Stage feature patch fp32 -> fp64 (zero borders).
  for (int i = t; i < 4 * 42 * 32; i += 512) {
    int c = i & 31;
    int rc = i >> 5;
    int col = rc % 42;
    int row = rc / 42;
    int gy = y0 - 1 + row;
    int gx = col - 1;
    double v = 0.0;
    if (gy >= 0 && gy < H && gx >= 0 && gx < W)
      v = (double)feat[(gy * W + gx) * CIN + c0 + c];
    patch[row][col][c] = v;
  }
  __syncthreads();

  const int wave = t >> 6, lane = t & 63;
  const int nl = lane & 15;   // A: m-index, B: n-index (assumed feed layout)
  const int kk = lane >> 4;   // k-index within K=4 step
  const int n0 = wave * 32;

  // --- D-layout self-calibration probes -----------------------------------
  // Probe 1 (column): A[m][k]=delta(k==0) (ones col), B[0][n]=n  => D[m][n]=n
  // Probe 2 (row):    A[m][0]=m,           B[k][n]=delta(k==0)   => D[m][n]=m
  d4 zero = (d4)0.0;
  double pa1 = (kk == 0) ? 1.0 : 0.0;
  double pb1 = (kk == 0) ? (double)nl : 0.0;
  d4 dcol = __builtin_amdgcn_mfma_f64_16x16x4f64(pa1, pb1, zero, 0, 0, 0);
  double pa2 = (kk == 0) ? (double)nl : 0.0;
  double pb2 = (kk == 0) ? 1.0 : 0.0;
  d4 drow = __builtin_amdgcn_mfma_f64_16x16x4f64(pa2, pb2, zero, 0, 0, 0);

  int apy[5], apx[5];
#pragma unroll
  for (int f = 0; f < 5; ++f) {
    int pos = f * 16 + nl;
    apy[f] = pos / 40;
    apx[f] = pos % 40;
  }

  d4 acc[5][2];
#pragma unroll
  for (int f = 0; f < 5; ++f)
#pragma unroll
    for (int g = 0; g < 2; ++g) acc[f][g] = (d4)0.0;

  for (int tap = 0; tap < 9; ++tap) {
    const int dy = tap / 3, dx = tap % 3;
    const double* ap0 = &patch[apy[0] + dy][apx[0] + dx][kk];
    const double* ap1 = &patch[apy[1] + dy][apx[1] + dx][kk];
    const double* ap2 = &patch[apy[2] + dy][apx[2] + dx][kk];
    const double* ap3 = &patch[apy[3] + dy][apx[3] + dx][kk];
    const double* ap4 = &patch[apy[4] + dy][apx[4] + dx][kk];
    const float* bp = conv_w + ((tap * CIN + c0 + kk) * CMID + n0 + nl);
#pragma unroll
    for (int cq = 0; cq < 8; ++cq) {
      const int co = cq * 4;  // element offset along c within patch row
      double b0 = (double)bp[co * CMID];
      double b1 = (double)bp[co * CMID + 16];
      double a0 = ap0[co];
      double a1 = ap1[co];
      double a2 = ap2[co];
      double a3 = ap3[co];
      double a4 = ap4[co];
      acc[0][0] = __builtin_amdgcn_mfma_f64_16x16x4f64(a0, b0, acc[0][0], 0, 0, 0);
      acc[0][1] = __builtin_amdgcn_mfma_f64_16x16x4f64(a0, b1, acc[0][1], 0, 0, 0);
      acc[1][0] = __builtin_amdgcn_mfma_f64_16x16x4f64(a1, b0, acc[1][0], 0, 0, 0);
      acc[1][1] = __builtin_amdgcn_mfma_f64_16x16x4f64(a1, b1, acc[1][1], 0, 0, 0);
      acc[2][0] = __builtin_amdgcn_mfma_f64_16x16x4f64(a2, b0, acc[2][0], 0, 0, 0);
      acc[2][1] = __builtin_amdgcn_mfma_f64_16x16x4f64(a2, b1, acc[2][1], 0, 0, 0);
      acc[3][0] = __builtin_amdgcn_mfma_f64_16x16x4f64(a3, b0, acc[3][0], 0, 0, 0);
      acc[3][1] = __builtin_amdgcn_mfma_f64_16x16x4f64(a3, b1, acc[3][1], 0, 0, 0);
      acc[4][0] = __builtin_amdgcn_mfma_f64_16x16x4f64(a4, b0, acc[4][0], 0, 0, 0);
      acc[4][1] = __builtin_amdgcn_mfma_f64_16x16x4f64(a4, b1, acc[4][1], 0, 0, 0);
    }
  }

  // Scatter using the PROBED D mapping: element i of this lane's accumulator
  // sits at (row=drow[i], col=dcol[i]) of the 16x16 tile — whatever the HW
  // layout is. Combine K-splits via fp64 atomicAdd.
#pragma unroll
  for (int f = 0; f < 5; ++f)
#pragma unroll
    for (int g = 0; g < 2; ++g)
#pragma unroll
      for (int i = 0; i < 4; ++i) {
        int pm = (int)drow[i];
        int pn = (int)dcol[i];
        int pos = f * 16 + pm;
        int py = pos / 40, px = pos % 40;
        int gpos = (y0 + py) * W + px;
        atomicAdd(&xsum[gpos * CMID + n0 + g * 16 + pn], acc[f][g][i]);
      }
}

// ---------------------------------------------------------------------------
// Kernel 2: bias+ReLU, cls (10) + reg (20) 1x1 convs in fp64, sigmoid score,
// anchor box decode. One block per spatial position.
// ---------------------------------------------------------------------------
__global__ __launch_bounds__(256) void heads_kernel(
    const double* __restrict__ xsum, const float* __restrict__ conv_b,
    const float* __restrict__ cls_w, const float* __restrict__ cls_b,
    const float* __restrict__ reg_w, const float* __restrict__ reg_b,
    double* __restrict__ scores, double* __restrict__ boxes) {
  __shared__ double xd[256];
  __shared__ double outv[32];
  const int p = blockIdx.x;
  const int t = threadIdx.x;
  double v = xsum[p * 256 + t] + (double)conv_b[t];
  xd[t] = v > 0.0 ? v : 0.0;
  __syncthreads();

  const int wave = t >> 6, lane = t & 63;
  for (int q = 0; q < 8; ++q) {
    int o = wave * 8 + q;
    if (o < 30) {  // uniform within wave
      double acc = 0.0;
      if (o < 10) {
#pragma unroll
        for (int k = 0; k < 4; ++k)
          acc += xd[lane * 4 + k] * (double)cls_w[(lane * 4 + k) * 10 + o];
      } else {
        int oo = o - 10;
#pragma unroll
        for (int k = 0; k < 4; ++k)
          acc += xd[lane * 4 + k] * (double)reg_w[(lane * 4 + k) * 20 + oo];
      }
#pragma unroll
      for (int off = 32; off > 0; off >>= 1) acc += __shfl_down(acc, off);
      if (lane == 0) outv[o] = acc;
    }
  }
  __syncthreads();

  if (t < 5) {
    const int a = t;
    double l0 = outv[2 * a] + (double)cls_b[2 * a];
    double l1 = outv[2 * a + 1] + (double)cls_b[2 * a + 1];
    double sc = 1.0 / (1.0 + exp(l0 - l1));  // == softmax[...,1]
    const int n = p * 5 + a;
    scores[n] = sc;
    double d0 = outv[10 + 4 * a + 0] + (double)reg_b[4 * a + 0];
    double d1 = outv[10 + 4 * a + 1] + (double)reg_b[4 * a + 1];
    double d2 = outv[10 + 4 * a + 2] + (double)reg_b[4 * a + 2];
    double d3 = outv[10 + 4 * a + 3] + (double)reg_b[4 * a + 3];
    double scale = (double)(32 << a);  // 32,64,128,256,512 (ratio=1)
    double wdt = exp(d2) * scale;
    double hgt = exp(d3) * scale;
    double xc = (double)(p % W) + d0;  // FEATURE_STRIDE = 1
    double yc = (double)(p / W) + d1;
    boxes[n * 4 + 0] = xc - 0.5 * wdt;
    boxes[n * 4 + 1] = yc - 0.5 * hgt;
    boxes[n * 4 + 2] = xc + 0.5 * wdt;
    boxes[n * 4 + 3] = yc + 0.5 * hgt;
  }
}

// ---------------------------------------------------------------------------
// Kernel 3: exact stable descending argsort via O(N^2) rank counting.
// ---------------------------------------------------------------------------
__global__ __launch_bounds__(256) void rank_kernel(
    const double* __restrict__ scores, const double* __restrict__ boxes,
    double* __restrict__ bs, double* __restrict__ area) {
  __shared__ double sch[1024];
  const int t = threadIdx.x;
  const int i = blockIdx.x * 256 + t;
  const bool act = i < NBOX;
  const double si = act ? scores[i] : 0.0;
  int cnt = 0;
  for (int base = 0; base < NBOX; base += 1024) {
    const int lim = min(1024, NBOX - base);
    __syncthreads();
#pragma unroll
    for (int q = 0; q < 4; ++q) {
      int j = base + t * 4 + q;
      sch[t * 4 + q] = (j < NBOX) ? scores[j] : -1.0;
    }
    __syncthreads();
    for (int jj = 0; jj < lim; jj += 2) {
      double a0 = sch[jj], a1 = sch[jj + 1];
      int j0 = base + jj;
      cnt += (a0 > si || (a0 == si && j0 < i)) ? 1 : 0;
      cnt += (a1 > si || (a1 == si && (j0 + 1) < i)) ? 1 : 0;
    }
  }
  if (act) {
    double b0 = boxes[i * 4 + 0], b1 = boxes[i * 4 + 1];
    double b2 = boxes[i * 4 + 2], b3 = boxes[i * 4 + 3];
    bs[cnt * 4 + 0] = b0;
    bs[cnt * 4 + 1] = b1;
    bs[cnt * 4 + 2] = b2;
    bs[cnt * 4 + 3] = b3;
    area[cnt] = (b2 - b0) * (b3 - b1);
  }
}

// ---------------------------------------------------------------------------
// Kernel 4a: suppression bit-matrix. Row i, word tj: bit l set iff
// j = tj*64+l has j>i and iou(i,j) >= 0.7. Div-free compare:
// inter >= 0.7*(ai+aj-inter)  (union always > 0; identical decision).
// Grid: 125*125 tiles of 64(i) x 64(j); block 256 = 4 waves x 16 i each.
// ---------------------------------------------------------------------------
__global__ __launch_bounds__(256) void iou_matrix_kernel(
    const double* __restrict__ bs, const double* __restrict__ area,
    unsigned long long* __restrict__ supmat) {
  __shared__ double jx1[64], jy1[64], jx2[64], jy2[64], ja[64];
  __shared__ double ix1[64], iy1[64], ix2[64], iy2[64], ia[64];
  const int ti = blockIdx.x / NCH, tj = blockIdx.x % NCH;
  const int t = threadIdx.x, wv = t >> 6, lane = t & 63;
  if (t < 64) {
    int j = tj * 64 + t;
    jx1[t] = bs[j * 4 + 0];
    jy1[t] = bs[j * 4 + 1];
    jx2[t] = bs[j * 4 + 2];
    jy2[t] = bs[j * 4 + 3];
    ja[t] = area[j];
  } else if (t < 128) {
    int l = t - 64;
    int i = ti * 64 + l;
    ix1[l] = bs[i * 4 + 0];
    iy1[l] = bs[i * 4 + 1];
    ix2[l] = bs[i * 4 + 2];
    iy2[l] = bs[i * 4 + 3];
    ia[l] = area[i];
  }
  __syncthreads();
  const double x1 = jx1[lane], y1 = jy1[lane], x2 = jx2[lane], y2 = jy2[lane];
  const double aj = ja[lane];
  const int jglob = tj * 64 + lane;
#pragma unroll 4
  for (int s = 0; s < 16; ++s) {
    const int il = wv * 16 + s;
    const int i = ti * 64 + il;
    const double bx1 = ix1[il], by1 = iy1[il], bx2 = ix2[il], by2 = iy2[il];
    const double ai = ia[il];
    double iw = fmin(x2, bx2) - fmax(x1, bx1);
    iw = iw > 0.0 ? iw : 0.0;
    double ih = fmin(y2, by2) - fmax(y1, by1);
    ih = ih > 0.0 ? ih : 0.0;
    double inter = iw * ih;
    bool sup = (jglob > i) && (inter >= 0.7 * (ai + aj - inter));
    unsigned long long wmask = __ballot(sup ? 1 : 0);
    if (lane == 0) supmat[(size_t)i * ROWW + tj] = wmask;
  }
}

// ---------------------------------------------------------------------------
// Kernel 4b: serial greedy resolution over the bit-matrix. ONE wave.
// ---------------------------------------------------------------------------
__global__ __launch_bounds__(64) void nms_serial_kernel(
    const double* __restrict__ bs,
    const unsigned long long* __restrict__ supmat,
    float* __restrict__ rois_out) {
  __shared__ unsigned long long mask[NCH];
  __shared__ int selK[MAXDET];
  const int lane = threadIdx.x;

  mask[lane] = 0ull;
  if (lane + 64 < NCH) mask[lane + 64] = 0ull;
  __syncthreads();

  int nk = 0;
  // prefetch chunk 0 diagonal words
  unsigned long long wdiag = supmat[(size_t)lane * ROWW + 0];

  for (int tc = 0; tc < NCH && nk < MAXDET; ++tc) {
    unsigned long long m = mask[tc];   // broadcast LDS read (uniform)
    unsigned long long wcur = wdiag;
    // prefetch next chunk's diagonal words (overlaps with serial phase)
    unsigned long long wnext = 0ull;
    if (tc + 1 < NCH)
      wnext = supmat[(size_t)((tc + 1) * 64 + lane) * ROWW + (tc + 1)];

    unsigned long long cand = ~m;      // all 64 boxes valid (8000 = 125*64)
    unsigned long long keptbits = 0ull;
    while (cand && nk < MAXDET) {      // fully uniform loop
      int b = __ffsll(cand) - 1;       // lowest-ranked unsuppressed candidate
      unsigned long long bit = 1ull << b;
      keptbits |= bit;
      if (lane == 0) selK[nk] = tc * 64 + b;
      nk++;
      unsigned long long row = __shfl(wcur, b);  // its in-chunk suppressions
      cand &= ~(row | bit);
    }
    // propagate kept rows into future mask words (parallel over lanes)
    unsigned long long kb = keptbits;
    while (kb) {
      int b = __ffsll(kb) - 1;
      kb &= kb - 1;
      const size_t rbase = (size_t)(tc * 64 + b) * ROWW;
      for (int w = tc + 1 + lane; w < NCH; w += 64)
        mask[w] |= supmat[rbase + w];
    }
    wdiag = wnext;
    __syncthreads();  // mask writes visible before next chunk's read
  }
  __syncthreads();

  const int NK = nk;  // uniform
  for (int r = lane; r < MAXDET; r += 64) {
    if (r < NK) {
      int p = selK[r];
      rois_out[r * 4 + 0] = (float)bs[p * 4 + 0];
      rois_out[r * 4 + 1] = (float)bs[p * 4 + 1];
      rois_out[r * 4 + 2] = (float)bs[p * 4 + 2];
      rois_out[r * 4 + 3] = (float)bs[p * 4 + 3];
    } else {  // rois = b[sel] * 0 exactly
      rois_out[r * 4 + 0] = 0.f;
      rois_out[r * 4 + 1] = 0.f;
      rois_out[r * 4 + 2] = 0.f;
      rois_out[r * 4 + 3] = 0.f;
    }
  }
}

// ---------------------------------------------------------------------------
// Kernel 5: FC head (fp32; tolerances generous, softmax saturated).
// ---------------------------------------------------------------------------
__global__ __launch_bounds__(256) void rcnn_head_kernel(
    const float* __restrict__ rois, const float* __restrict__ fc1_w,
    const float* __restrict__ fc1_b, const float* __restrict__ clsh_w,
    const float* __restrict__ clsh_b, const float* __restrict__ regh_w,
    const float* __restrict__ regh_b, float* __restrict__ out) {
  __shared__ float red[256 * 8];
  const int r = blockIdx.x, t = threadIdx.x;
  const float r0 = rois[r * 4 + 0], r1 = rois[r * 4 + 1];
  const float r2 = rois[r * 4 + 2], r3 = rois[r * 4 + 3];
  float pc[4] = {0, 0, 0, 0}, pb[4] = {0, 0, 0, 0};
#pragma unroll
  for (int q = 0; q < 4; ++q) {
    int j = t * 4 + q;
    float f = r0 * fc1_w[j] + r1 * fc1_w[1024 + j] + r2 * fc1_w[2048 + j] +
              r3 * fc1_w[3072 + j] + fc1_b[j];
    f = fmaxf(f, 0.f);
#pragma unroll
    for (int c = 0; c < 4; ++c) {
      pc[c] += f * clsh_w[j * 4 + c];
      pb[c] += f * regh_w[j * 4 + c];
    }
  }
#pragma unroll
  for (int u = 0; u < 4; ++u) {
    red[t * 8 + u] = pc[u];
    red[t * 8 + 4 + u] = pb[u];
  }
  __syncthreads();
  for (int s = 128; s > 0; s >>= 1) {
    if (t < s) {
#pragma unroll
      for (int u = 0; u < 8; ++u) red[t * 8 + u] += red[(t + s) * 8 + u];
    }
    __syncthreads();
  }
  if (t == 0) {
    float lg[4];
    float m = -1e30f;
#pragma unroll
    for (int c = 0; c < 4; ++c) {
      lg[c] = red[c] + clsh_b[c];
      m = fmaxf(m, lg[c]);
    }
    float s = 0.f;
#pragma unroll
    for (int c = 0; c < 4; ++c) {
      lg[c] = expf(lg[c] - m);
      s += lg[c];
    }
#pragma unroll
    for (int c = 0; c < 4; ++c) out[r * 4 + c] = lg[c] / s;
#pragma unroll
    for (int k = 0; k < 4; ++k)
      out[1200 + r * 4 + k] = red[4 + k] + regh_b[k];
  }
}

// ---------------------------------------------------------------------------
extern "C" void kernel_launch(void* const* d_in, const int* in_sizes, int n_in,
                              void* d_out, int out_size, void* d_ws,
                              size_t ws_size, hipStream_t stream) {
  const float* feat = (const float*)d_in[0];
  const float* conv_w = (const float*)d_in[1];
  const float* conv_b = (const float*)d_in[2];
  const float* cls_w = (const float*)d_in[3];
  const float* cls_b = (const float*)d_in[4];
  const float* reg_w = (const float*)d_in[5];
  const float* reg_b = (const float*)d_in[6];
  const float* fc1_w = (const float*)d_in[7];
  const float* fc1_b = (const float*)d_in[8];
  const float* clsh_w = (const float*)d_in[9];
  const float* clsh_b = (const float*)d_in[10];
  const float* regh_w = (const float*)d_in[11];
  const float* regh_b = (const float*)d_in[12];
  float* out = (float*)d_out;

  char* w = (char*)d_ws;
  double* xsum = (double*)(w);                 // 1600*256*8   = 3,276,800 B
  double* scores = (double*)(w + 3276800);     // 8000*8       =    64,000 B
  double* boxes = (double*)(w + 3340800);      // 8000*4*8     =   256,000 B
  double* bs = (double*)(w + 3596800);         // 8000*4*8     =   256,000 B
  double* area = (double*)(w + 3852800);       // 8000*8       =    64,000 B
  unsigned long long* supmat =
      (unsigned long long*)(w + 3916800);      // 8000*128*8   = 8,192,000 B

  hipMemsetAsync(xsum, 0, 3276800, stream);
  conv3x3_kernel<<<1280, 512, 0, stream>>>(feat, conv_w, xsum);
  heads_kernel<<<1600, 256, 0, stream>>>(xsum, conv_b, cls_w, cls_b, reg_w,
                                         reg_b, scores, boxes);
  rank_kernel<<<32, 256, 0, stream>>>(scores, boxes, bs, area);
  iou_matrix_kernel<<<NCH * NCH, 256, 0, stream>>>(bs, area, supmat);
  nms_serial_kernel<<<1, 64, 0, stream>>>(bs, supmat, out + 2400);
  rcnn_head_kernel<<<300, 256, 0, stream>>>(out + 2400, fc1_w, fc1_b, clsh_w,
                                            clsh_b, regh_w, regh_b, out);
}

// Round 5
// 847.512 us; speedup vs baseline: 1.7025x; 1.0537x over previous
//
#include <hip/hip_runtime.h>
#include <math.h>

// ---------------------------------------------------------------------------
// Faster-RCNN head pipeline on gfx950.
// Precision strategy: everything that affects NMS *selection* (conv, cls/reg
// heads, scores, boxes, IoU) is computed in fp64 so our ordering matches the
// numpy f64 reference ordering except for true ties (prob ~0). The final FC
// head is fp32 (outputs have generous thresholds / saturated softmax).
//
// R1: NMS 762us -> iou bit-matrix (parallel) + 1-wave serial resolution.
// R2: conv3x3 -> v_mfma_f64_16x16x4 implicit GEMM. FAILED: f64 C/D layout
//     differs from bf16-family assumption.
// R3: probe-calibrated D scatter (2 probe MFMAs discover (row,col) per reg).
//     PASS 893us; conv 320us @ 1 block/CU (acc regs >128 halve occupancy).
// R4: conv re-tiled: wave=1 N-frag (acc 40 VGPR), K=64/block (2 LDS slabs),
//     launch_bounds(512,4) -> 2 blocks/CU; atomics halved. nms_serial
//     propagate: register-accumulated ORs (one load latency per chunk, not
//     one per kept bit). iou_matrix: skip lower-triangle tiles.
// ---------------------------------------------------------------------------

#define H 40
#define W 40
#define CIN 2048
#define CMID 256
#define NBOX 8000   // 40*40*5
#define NCH 125     // NBOX / 64 chunks
#define ROWW 128    // padded row width (ullong words) of suppression matrix
#define MAXDET 300

typedef double d4 __attribute__((ext_vector_type(4)));

// ---------------------------------------------------------------------------
// Kernel 1: 3x3 SAME conv (2048 -> 256) via v_mfma_f64_16x16x4.
// Grid 1280 = 20 M-tiles (2 rows = 80 pos = 5 frags) x 2 N-halves (128 ch)
//            x 32 K-splits (64 in-ch each, staged as two 32-ch LDS slabs).
// Block 512 = 8 waves; wave w owns 16 outch (1 N-frag) -> acc = 5 x d4.
// Operand feeding: A[m][k]: m=lane&15, k=lane>>4; B[k][n]: n=lane&15.
// D mapping discovered at runtime via probe MFMAs (f64 layout is NOT the
// bf16-family one — verified R2/R3).
// ---------------------------------------------------------------------------
__global__ __launch_bounds__(512, 4) void conv3x3_kernel(
    const float* __restrict__ feat, const float* __restrict__ conv_w,
    double* __restrict__ xsum) {
  __shared__ double patch[4][42][33];  // rows y0-1..y0+2, cols -1..40, 32ch+pad
  const int t = threadIdx.x;
  const int blk = blockIdx.x;
  const int sk = blk & 31;          // K-split: channels c0..c0+63
  const int nh = (blk >> 5) & 1;    // N-half: outch nh*128..+128
  const int mt = blk >> 6;          // M-tile: rows y0, y0+1
  const int y0 = mt * 2;
  const int c0 = sk * 64;

  const int wave = t >> 6, lane = t & 63;
  const int nl = lane & 15;   // A: m-index, B: n-index
  const int kk = lane >> 4;   // k-index within K=4 step
  const int n1 = nh * 128 + wave * 16;

  // --- D-layout self-calibration probes (cost: 2 MFMAs) -------------------
  // Probe col: A[m][k]=delta(k==0), B[0][n]=n  => D[m][n]=n
  // Probe row: A[m][0]=m,           B[k][n]=delta(k==0) => D[m][n]=m
  d4 zero = (d4)0.0;
  double pa1 = (kk == 0) ? 1.0 : 0.0;
  double pb1 = (kk == 0) ? (double)nl : 0.0;
  d4 dcol = __builtin_amdgcn_mfma_f64_16x16x4f64(pa1, pb1, zero, 0, 0, 0);
  double pa2 = (kk == 0) ? (double)nl : 0.0;
  double pb2 = (kk == 0) ? 1.0 : 0.0;
  d4 drow = __builtin_amdgcn_mfma_f64_16x16x4f64(pa2, pb2, zero, 0, 0, 0);

  int apy[5], apx[5];
#pragma unroll
  for (int f = 0; f < 5; ++f) {
    int pos = f * 16 + nl;
    apy[f] = pos / 40;
    apx[f] = pos % 40;
  }

  d4 acc[5];
#pragma unroll
  for (int f = 0; f < 5; ++f) acc[f] = (d4)0.0;

  for (int s2 = 0; s2 < 2; ++s2) {
    const int ch = c0 + s2 * 32;
    if (s2) __syncthreads();  // previous slab fully consumed
    // Stage feature slab fp32 -> fp64 (zero borders).
    for (int i = t; i < 4 * 42 * 32; i += 512) {
      int c = i & 31;
      int rc = i >> 5;
      int col = rc % 42;
      int row = rc / 42;
      int gy = y0 - 1 + row;
      int gx = col - 1;
      double v = 0.0;
      if (gy >= 0 && gy < H && gx >= 0 && gx < W)
        v = (double)feat[(gy * W + gx) * CIN + ch + c];
      patch[row][col][c] = v;
    }
    __syncthreads();

    for (int tap = 0; tap < 9; ++tap) {
      const int dy = tap / 3, dx = tap % 3;
      const double* ap0 = &patch[apy[0] + dy][apx[0] + dx][kk];
      const double* ap1 = &patch[apy[1] + dy][apx[1] + dx][kk];
      const double* ap2 = &patch[apy[2] + dy][apx[2] + dx][kk];
      const double* ap3 = &patch[apy[3] + dy][apx[3] + dx][kk];
      const double* ap4 = &patch[apy[4] + dy][apx[4] + dx][kk];
      const float* bp = conv_w + ((tap * CIN + ch + kk) * CMID + n1 + nl);
#pragma unroll
      for (int cq = 0; cq < 8; ++cq) {
        const int co = cq * 4;  // channel offset within slab (K=4 group base)
        double b0 = (double)bp[co * CMID];
        double a0 = ap0[co];
        double a1 = ap1[co];
        double a2 = ap2[co];
        double a3 = ap3[co];
        double a4 = ap4[co];
        acc[0] = __builtin_amdgcn_mfma_f64_16x16x4f64(a0, b0, acc[0], 0, 0, 0);
        acc[1] = __builtin_amdgcn_mfma_f64_16x16x4f64(a1, b0, acc[1], 0, 0, 0);
        acc[2] = __builtin_amdgcn_mfma_f64_16x16x4f64(a2, b0, acc[2], 0, 0, 0);
        acc[3] = __builtin_amdgcn_mfma_f64_16x16x4f64(a3, b0, acc[3], 0, 0, 0);
        acc[4] = __builtin_amdgcn_mfma_f64_16x16x4f64(a4, b0, acc[4], 0, 0, 0);
      }
    }
  }

  // Scatter via PROBED D mapping; combine K-splits with fp64 atomicAdd.
#pragma unroll
  for (int f = 0; f < 5; ++f)
#pragma unroll
    for (int i = 0; i < 4; ++i) {
      int pm = (int)drow[i];
      int pn = (int)dcol[i];
      int pos = f * 16 + pm;
      int py = pos / 40, px = pos % 40;
      int gpos = (y0 + py) * W + px;
      atomicAdd(&xsum[gpos * CMID + n1 + pn], acc[f][i]);
    }
}

// ---------------------------------------------------------------------------
// Kernel 2: bias+ReLU, cls (10) + reg (20) 1x1 convs in fp64, sigmoid score,
// anchor box decode. One block per spatial position.
// ---------------------------------------------------------------------------
__global__ __launch_bounds__(256) void heads_kernel(
    const double* __restrict__ xsum, const float* __restrict__ conv_b,
    const float* __restrict__ cls_w, const float* __restrict__ cls_b,
    const float* __restrict__ reg_w, const float* __restrict__ reg_b,
    double* __restrict__ scores, double* __restrict__ boxes) {
  __shared__ double xd[256];
  __shared__ double outv[32];
  const int p = blockIdx.x;
  const int t = threadIdx.x;
  double v = xsum[p * 256 + t] + (double)conv_b[t];
  xd[t] = v > 0.0 ? v : 0.0;
  __syncthreads();

  const int wave = t >> 6, lane = t & 63;
  for (int q = 0; q < 8; ++q) {
    int o = wave * 8 + q;
    if (o < 30) {  // uniform within wave
      double acc = 0.0;
      if (o < 10) {
#pragma unroll
        for (int k = 0; k < 4; ++k)
          acc += xd[lane * 4 + k] * (double)cls_w[(lane * 4 + k) * 10 + o];
      } else {
        int oo = o - 10;
#pragma unroll
        for (int k = 0; k < 4; ++k)
          acc += xd[lane * 4 + k] * (double)reg_w[(lane * 4 + k) * 20 + oo];
      }
#pragma unroll
      for (int off = 32; off > 0; off >>= 1) acc += __shfl_down(acc, off);
      if (lane == 0) outv[o] = acc;
    }
  }
  __syncthreads();

  if (t < 5) {
    const int a = t;
    double l0 = outv[2 * a] + (double)cls_b[2 * a];
    double l1 = outv[2 * a + 1] + (double)cls_b[2 * a + 1];
    double sc = 1.0 / (1.0 + exp(l0 - l1));  // == softmax[...,1]
    const int n = p * 5 + a;
    scores[n] = sc;
    double d0 = outv[10 + 4 * a + 0] + (double)reg_b[4 * a + 0];
    double d1 = outv[10 + 4 * a + 1] + (double)reg_b[4 * a + 1];
    double d2 = outv[10 + 4 * a + 2] + (double)reg_b[4 * a + 2];
    double d3 = outv[10 + 4 * a + 3] + (double)reg_b[4 * a + 3];
    double scale = (double)(32 << a);  // 32,64,128,256,512 (ratio=1)
    double wdt = exp(d2) * scale;
    double hgt = exp(d3) * scale;
    double xc = (double)(p % W) + d0;  // FEATURE_STRIDE = 1
    double yc = (double)(p / W) + d1;
    boxes[n * 4 + 0] = xc - 0.5 * wdt;
    boxes[n * 4 + 1] = yc - 0.5 * hgt;
    boxes[n * 4 + 2] = xc + 0.5 * wdt;
    boxes[n * 4 + 3] = yc + 0.5 * hgt;
  }
}

// ---------------------------------------------------------------------------
// Kernel 3: exact stable descending argsort via O(N^2) rank counting.
// ---------------------------------------------------------------------------
__global__ __launch_bounds__(256) void rank_kernel(
    const double* __restrict__ scores, const double* __restrict__ boxes,
    double* __restrict__ bs, double* __restrict__ area) {
  __shared__ double sch[1024];
  const int t = threadIdx.x;
  const int i = blockIdx.x * 256 + t;
  const bool act = i < NBOX;
  const double si = act ? scores[i] : 0.0;
  int cnt = 0;
  for (int base = 0; base < NBOX; base += 1024) {
    const int lim = min(1024, NBOX - base);
    __syncthreads();
#pragma unroll
    for (int q = 0; q < 4; ++q) {
      int j = base + t * 4 + q;
      sch[t * 4 + q] = (j < NBOX) ? scores[j] : -1.0;
    }
    __syncthreads();
    for (int jj = 0; jj < lim; jj += 2) {
      double a0 = sch[jj], a1 = sch[jj + 1];
      int j0 = base + jj;
      cnt += (a0 > si || (a0 == si && j0 < i)) ? 1 : 0;
      cnt += (a1 > si || (a1 == si && (j0 + 1) < i)) ? 1 : 0;
    }
  }
  if (act) {
    double b0 = boxes[i * 4 + 0], b1 = boxes[i * 4 + 1];
    double b2 = boxes[i * 4 + 2], b3 = boxes[i * 4 + 3];
    bs[cnt * 4 + 0] = b0;
    bs[cnt * 4 + 1] = b1;
    bs[cnt * 4 + 2] = b2;
    bs[cnt * 4 + 3] = b3;
    area[cnt] = (b2 - b0) * (b3 - b1);
  }
}

// ---------------------------------------------------------------------------
// Kernel 4a: suppression bit-matrix. Row i, word tj: bit l set iff
// j = tj*64+l has j>i and iou(i,j) >= 0.7. Div-free compare:
// inter >= 0.7*(ai+aj-inter)  (union always > 0; identical decision).
// Only tiles tj >= ti are ever read by the resolver -> early-exit others.
// ---------------------------------------------------------------------------
__global__ __launch_bounds__(256) void iou_matrix_kernel(
    const double* __restrict__ bs, const double* __restrict__ area,
    unsigned long long* __restrict__ supmat) {
  __shared__ double jx1[64], jy1[64], jx2[64], jy2[64], ja[64];
  __shared__ double ix1[64], iy1[64], ix2[64], iy2[64], ia[64];
  const int ti = blockIdx.x / NCH, tj = blockIdx.x % NCH;
  if (tj < ti) return;  // lower triangle never read
  const int t = threadIdx.x, wv = t >> 6, lane = t & 63;
  if (t < 64) {
    int j = tj * 64 + t;
    jx1[t] = bs[j * 4 + 0];
    jy1[t] = bs[j * 4 + 1];
    jx2[t] = bs[j * 4 + 2];
    jy2[t] = bs[j * 4 + 3];
    ja[t] = area[j];
  } else if (t < 128) {
    int l = t - 64;
    int i = ti * 64 + l;
    ix1[l] = bs[i * 4 + 0];
    iy1[l] = bs[i * 4 + 1];
    ix2[l] = bs[i * 4 + 2];
    iy2[l] = bs[i * 4 + 3];
    ia[l] = area[i];
  }
  __syncthreads();
  const double x1 = jx1[lane], y1 = jy1[lane], x2 = jx2[lane], y2 = jy2[lane];
  const double aj = ja[lane];
  const int jglob = tj * 64 + lane;
#pragma unroll 4
  for (int s = 0; s < 16; ++s) {
    const int il = wv * 16 + s;
    const int i = ti * 64 + il;
    const double bx1 = ix1[il], by1 = iy1[il], bx2 = ix2[il], by2 = iy2[il];
    const double ai = ia[il];
    double iw = fmin(x2, bx2) - fmax(x1, bx1);
    iw = iw > 0.0 ? iw : 0.0;
    double ih = fmin(y2, by2) - fmax(y1, by1);
    ih = ih > 0.0 ? ih : 0.0;
    double inter = iw * ih;
    bool sup = (jglob > i) && (inter >= 0.7 * (ai + aj - inter));
    unsigned long long wmask = __ballot(sup ? 1 : 0);
    if (lane == 0) supmat[(size_t)i * ROWW + tj] = wmask;
  }
}

// ---------------------------------------------------------------------------
// Kernel 4b: serial greedy resolution over the bit-matrix. ONE wave.
// Per chunk: diag-word gather (prefetched 1 ahead), in-register shfl serial
// resolution, then REGISTER-ACCUMULATED propagate: each lane owns mask words
// w == tc+1+lane (+64); loads across kept bits are independent -> pipelined,
// one load-latency per chunk instead of one per kept bit.
// ---------------------------------------------------------------------------
__global__ __launch_bounds__(64) void nms_serial_kernel(
    const double* __restrict__ bs,
    const unsigned long long* __restrict__ supmat,
    float* __restrict__ rois_out) {
  __shared__ unsigned long long mask[NCH];
  __shared__ int selK[MAXDET];
  const int lane = threadIdx.x;

  mask[lane] = 0ull;
  if (lane + 64 < NCH) mask[lane + 64] = 0ull;
  __syncthreads();

  int nk = 0;
  unsigned long long wdiag = supmat[(size_t)lane * ROWW + 0];

  for (int tc = 0; tc < NCH && nk < MAXDET; ++tc) {
    unsigned long long m = mask[tc];   // broadcast LDS read (uniform)
    unsigned long long wcur = wdiag;
    unsigned long long wnext = 0ull;   // prefetch next chunk's diag words
    if (tc + 1 < NCH)
      wnext = supmat[(size_t)((tc + 1) * 64 + lane) * ROWW + (tc + 1)];

    unsigned long long cand = ~m;      // all 64 boxes valid (8000 = 125*64)
    unsigned long long keptbits = 0ull;
    while (cand && nk < MAXDET) {      // fully uniform loop
      int b = __ffsll(cand) - 1;
      unsigned long long bit = 1ull << b;
      keptbits |= bit;
      if (lane == 0) selK[nk] = tc * 64 + b;
      nk++;
      unsigned long long row = __shfl(wcur, b);
      cand &= ~(row | bit);
    }
    // Propagate kept rows into future mask words. Lane owns words
    // w0 = tc+1+lane and w1 = w0+64 (each word touched by exactly one lane).
    unsigned long long a0 = 0ull, a1 = 0ull;
    const int w0 = tc + 1 + lane, w1 = tc + 65 + lane;
    unsigned long long kb = keptbits;
    while (kb) {
      int b = __ffsll(kb) - 1;
      kb &= kb - 1;
      const unsigned long long* rp = supmat + (size_t)(tc * 64 + b) * ROWW;
      if (w0 < NCH) a0 |= rp[w0];
      if (w1 < NCH) a1 |= rp[w1];
    }
    if (w0 < NCH) mask[w0] |= a0;
    if (w1 < NCH) mask[w1] |= a1;
    wdiag = wnext;
    __syncthreads();  // mask writes visible before next chunk's read
  }
  __syncthreads();

  const int NK = nk;  // uniform
  for (int r = lane; r < MAXDET; r += 64) {
    if (r < NK) {
      int p = selK[r];
      rois_out[r * 4 + 0] = (float)bs[p * 4 + 0];
      rois_out[r * 4 + 1] = (float)bs[p * 4 + 1];
      rois_out[r * 4 + 2] = (float)bs[p * 4 + 2];
      rois_out[r * 4 + 3] = (float)bs[p * 4 + 3];
    } else {  // rois = b[sel] * 0 exactly
      rois_out[r * 4 + 0] = 0.f;
      rois_out[r * 4 + 1] = 0.f;
      rois_out[r * 4 + 2] = 0.f;
      rois_out[r * 4 + 3] = 0.f;
    }
  }
}

// ---------------------------------------------------------------------------
// Kernel 5: FC head (fp32; tolerances generous, softmax saturated).
// ---------------------------------------------------------------------------
__global__ __launch_bounds__(256) void rcnn_head_kernel(
    const float* __restrict__ rois, const float* __restrict__ fc1_w,
    const float* __restrict__ fc1_b, const float* __restrict__ clsh_w,
    const float* __restrict__ clsh_b, const float* __restrict__ regh_w,
    const float* __restrict__ regh_b, float* __restrict__ out) {
  __shared__ float red[256 * 8];
  const int r = blockIdx.x, t = threadIdx.x;
  const float r0 = rois[r * 4 + 0], r1 = rois[r * 4 + 1];
  const float r2 = rois[r * 4 + 2], r3 = rois[r * 4 + 3];
  float pc[4] = {0, 0, 0, 0}, pb[4] = {0, 0, 0, 0};
#pragma unroll
  for (int q = 0; q < 4; ++q) {
    int j = t * 4 + q;
    float f = r0 * fc1_w[j] + r1 * fc1_w[1024 + j] + r2 * fc1_w[2048 + j] +
              r3 * fc1_w[3072 + j] + fc1_b[j];
    f = fmaxf(f, 0.f);
#pragma unroll
    for (int c = 0; c < 4; ++c) {
      pc[c] += f * clsh_w[j * 4 + c];
      pb[c] += f * regh_w[j * 4 + c];
    }
  }
#pragma unroll
  for (int u = 0; u < 4; ++u) {
    red[t * 8 + u] = pc[u];
    red[t * 8 + 4 + u] = pb[u];
  }
  __syncthreads();
  for (int s = 128; s > 0; s >>= 1) {
    if (t < s) {
#pragma unroll
      for (int u = 0; u < 8; ++u) red[t * 8 + u] += red[(t + s) * 8 + u];
    }
    __syncthreads();
  }
  if (t == 0) {
    float lg[4];
    float m = -1e30f;
#pragma unroll
    for (int c = 0; c < 4; ++c) {
      lg[c] = red[c] + clsh_b[c];
      m = fmaxf(m, lg[c]);
    }
    float s = 0.f;
#pragma unroll
    for (int c = 0; c < 4; ++c) {
      lg[c] = expf(lg[c] - m);
      s += lg[c];
    }
#pragma unroll
    for (int c = 0; c < 4; ++c) out[r * 4 + c] = lg[c] / s;
#pragma unroll
    for (int k = 0; k < 4; ++k)
      out[1200 + r * 4 + k] = red[4 + k] + regh_b[k];
  }
}

// ---------------------------------------------------------------------------
extern "C" void kernel_launch(void* const* d_in, const int* in_sizes, int n_in,
                              void* d_out, int out_size, void* d_ws,
                              size_t ws_size, hipStream_t stream) {
  const float* feat = (const float*)d_in[0];
  const float* conv_w = (const float*)d_in[1];
  const float* conv_b = (const float*)d_in[2];
  const float* cls_w = (const float*)d_in[3];
  const float* cls_b = (const float*)d_in[4];
  const float* reg_w = (const float*)d_in[5];
  const float* reg_b = (const float*)d_in[6];
  const float* fc1_w = (const float*)d_in[7];
  const float* fc1_b = (const float*)d_in[8];
  const float* clsh_w = (const float*)d_in[9];
  const float* clsh_b = (const float*)d_in[10];
  const float* regh_w = (const float*)d_in[11];
  const float* regh_b = (const float*)d_in[12];
  float* out = (float*)d_out;

  char* w = (char*)d_ws;
  double* xsum = (double*)(w);                 // 1600*256*8   = 3,276,800 B
  double* scores = (double*)(w + 3276800);     // 8000*8       =    64,000 B
  double* boxes = (double*)(w + 3340800);      // 8000*4*8     =   256,000 B
  double* bs = (double*)(w + 3596800);         // 8000*4*8     =   256,000 B
  double* area = (double*)(w + 3852800);       // 8000*8       =    64,000 B
  unsigned long long* supmat =
      (unsigned long long*)(w + 3916800);      // 8000*128*8   = 8,192,000 B

  hipMemsetAsync(xsum, 0, 3276800, stream);
  conv3x3_kernel<<<1280, 512, 0, stream>>>(feat, conv_w, xsum);
  heads_kernel<<<1600, 256, 0, stream>>>(xsum, conv_b, cls_w, cls_b, reg_w,
                                         reg_b, scores, boxes);
  rank_kernel<<<32, 256, 0, stream>>>(scores, boxes, bs, area);
  iou_matrix_kernel<<<NCH * NCH, 256, 0, stream>>>(bs, area, supmat);
  nms_serial_kernel<<<1, 64, 0, stream>>>(bs, supmat, out + 2400);
  rcnn_head_kernel<<<300, 256, 0, stream>>>(out + 2400, fc1_w, fc1_b, clsh_w,
                                            clsh_b, regh_w, regh_b, out);
}

// Round 6
// 844.994 us; speedup vs baseline: 1.7076x; 1.0030x over previous
//
#include <hip/hip_runtime.h>
#include <math.h>

// ---------------------------------------------------------------------------
// Faster-RCNN head pipeline on gfx950.
// Precision strategy: everything that affects NMS *selection* (conv, cls/reg
// heads, scores, boxes, IoU) is computed in fp64 so our ordering matches the
// numpy f64 reference ordering except for true ties (prob ~0). The final FC
// head is fp32 (outputs have generous thresholds / saturated softmax).
//
// R1: NMS 762us -> iou bit-matrix (parallel) + 1-wave serial resolution.
// R2: conv3x3 -> v_mfma_f64_16x16x4 implicit GEMM. FAILED: f64 C/D layout
//     differs from bf16-family assumption.
// R3: probe-calibrated D scatter. PASS 893; conv 320 @ 1 block/CU.
// R4: wave=1 N-frag, K=64, 2 blocks/CU. conv 278 (MfmaUtil 73%). nms/iou
//     tweaks neutral -> latency model of that pair was wrong.
// R5: conv: S=64/K=32, grid 2560 = EXACTLY 5 rounds of 512 resident blocks
//     (was 2.5 -> ~17% tail); LDS padded >54.6KB to pin 2 blocks/CU.
//     nms_serial: 1024 thr, one thread per future mask word -> coalesced
//     propagate, one load-latency/chunk. rank: constant-bound unrolled loop.
// ---------------------------------------------------------------------------

#define H 40
#define W 40
#define CIN 2048
#define CMID 256
#define NBOX 8000   // 40*40*5
#define NCH 125     // NBOX / 64 chunks
#define ROWW 128    // padded row width (ullong words) of suppression matrix
#define MAXDET 300

typedef double d4 __attribute__((ext_vector_type(4)));

// ---------------------------------------------------------------------------
// Kernel 1: 3x3 SAME conv (2048 -> 256) via v_mfma_f64_16x16x4.
// Grid 2560 = 20 M-tiles (2 rows = 80 pos = 5 frags) x 2 N-halves (128 ch)
//            x 64 K-splits (32 in-ch each, one LDS slab).
// Block 512 = 8 waves; wave w owns 16 outch (1 N-frag) -> acc = 5 x d4.
// 2560 = 5 exact rounds of 512 resident (2 blocks/CU; LDS padded to force).
// Operand feeding: A[m][k]: m=lane&15, k=lane>>4; B[k][n]: n=lane&15.
// D mapping discovered at runtime via probe MFMAs (f64 layout is NOT the
// bf16-family one — verified R2/R3).
// ---------------------------------------------------------------------------
__global__ __launch_bounds__(512, 4) void conv3x3_kernel(
    const float* __restrict__ feat, const float* __restrict__ conv_w,
    double* __restrict__ xsum) {
  // inner dim padded 33->41 so LDS/block = 55104B > 160KB/3: pins 2 blocks/CU
  __shared__ double patch[4][42][41];
  const int t = threadIdx.x;
  const int blk = blockIdx.x;
  const int sk = blk & 63;          // K-split: channels c0..c0+31
  const int nh = (blk >> 6) & 1;    // N-half: outch nh*128..+128
  const int mt = blk >> 7;          // M-tile: rows y0, y0+1
  const int y0 = mt * 2;
  const int c0 = sk * 32;

  const int wave = t >> 6, lane = t & 63;
  const int nl = lane & 15;   // A: m-index, B: n-index
  const int kk = lane >> 4;   // k-index within K=4 step
  const int n1 = nh * 128 + wave * 16;

  // --- D-layout self-calibration probes (cost: 2 MFMAs) -------------------
  d4 zero = (d4)0.0;
  double pa1 = (kk == 0) ? 1.0 : 0.0;
  double pb1 = (kk == 0) ? (double)nl : 0.0;
  d4 dcol = __builtin_amdgcn_mfma_f64_16x16x4f64(pa1, pb1, zero, 0, 0, 0);
  double pa2 = (kk == 0) ? (double)nl : 0.0;
  double pb2 = (kk == 0) ? 1.0 : 0.0;
  d4 drow = __builtin_amdgcn_mfma_f64_16x16x4f64(pa2, pb2, zero, 0, 0, 0);

  // Stage feature slab fp32 -> fp64 (zero borders): rows y0-1..y0+2,
  // cols -1..40, channels c0..c0+31.
  for (int i = t; i < 4 * 42 * 32; i += 512) {
    int c = i & 31;
    int rc = i >> 5;
    int col = rc % 42;
    int row = rc / 42;
    int gy = y0 - 1 + row;
    int gx = col - 1;
    double v = 0.0;
    if (gy >= 0 && gy < H && gx >= 0 && gx < W)
      v = (double)feat[(gy * W + gx) * CIN + c0 + c];
    patch[row][col][c] = v;
  }

  int apy[5], apx[5];
#pragma unroll
  for (int f = 0; f < 5; ++f) {
    int pos = f * 16 + nl;
    apy[f] = pos / 40;
    apx[f] = pos % 40;
  }

  d4 acc[5];
#pragma unroll
  for (int f = 0; f < 5; ++f) acc[f] = (d4)0.0;

  __syncthreads();

  for (int tap = 0; tap < 9; ++tap) {
    const int dy = tap / 3, dx = tap % 3;
    const double* ap0 = &patch[apy[0] + dy][apx[0] + dx][kk];
    const double* ap1 = &patch[apy[1] + dy][apx[1] + dx][kk];
    const double* ap2 = &patch[apy[2] + dy][apx[2] + dx][kk];
    const double* ap3 = &patch[apy[3] + dy][apx[3] + dx][kk];
    const double* ap4 = &patch[apy[4] + dy][apx[4] + dx][kk];
    const float* bp = conv_w + ((tap * CIN + c0 + kk) * CMID + n1 + nl);
#pragma unroll
    for (int cq = 0; cq < 8; ++cq) {
      const int co = cq * 4;  // channel offset within slab (K=4 group base)
      double b0 = (double)bp[co * CMID];
      double a0 = ap0[co];
      double a1 = ap1[co];
      double a2 = ap2[co];
      double a3 = ap3[co];
      double a4 = ap4[co];
      acc[0] = __builtin_amdgcn_mfma_f64_16x16x4f64(a0, b0, acc[0], 0, 0, 0);
      acc[1] = __builtin_amdgcn_mfma_f64_16x16x4f64(a1, b0, acc[1], 0, 0, 0);
      acc[2] = __builtin_amdgcn_mfma_f64_16x16x4f64(a2, b0, acc[2], 0, 0, 0);
      acc[3] = __builtin_amdgcn_mfma_f64_16x16x4f64(a3, b0, acc[3], 0, 0, 0);
      acc[4] = __builtin_amdgcn_mfma_f64_16x16x4f64(a4, b0, acc[4], 0, 0, 0);
    }
  }

  // Scatter via PROBED D mapping; combine K-splits with fp64 atomicAdd.
#pragma unroll
  for (int f = 0; f < 5; ++f)
#pragma unroll
    for (int i = 0; i < 4; ++i) {
      int pm = (int)drow[i];
      int pn = (int)dcol[i];
      int pos = f * 16 + pm;
      int py = pos / 40, px = pos % 40;
      int gpos = (y0 + py) * W + px;
      atomicAdd(&xsum[gpos * CMID + n1 + pn], acc[f][i]);
    }
}

// ---------------------------------------------------------------------------
// Kernel 2: bias+ReLU, cls (10) + reg (20) 1x1 convs in fp64, sigmoid score,
// anchor box decode. One block per spatial position.
// ---------------------------------------------------------------------------
__global__ __launch_bounds__(256) void heads_kernel(
    const double* __restrict__ xsum, const float* __restrict__ conv_b,
    const float* __restrict__ cls_w, const float* __restrict__ cls_b,
    const float* __restrict__ reg_w, const float* __restrict__ reg_b,
    double* __restrict__ scores, double* __restrict__ boxes) {
  __shared__ double xd[256];
  __shared__ double outv[32];
  const int p = blockIdx.x;
  const int t = threadIdx.x;
  double v = xsum[p * 256 + t] + (double)conv_b[t];
  xd[t] = v > 0.0 ? v : 0.0;
  __syncthreads();

  const int wave = t >> 6, lane = t & 63;
  for (int q = 0; q < 8; ++q) {
    int o = wave * 8 + q;
    if (o < 30) {  // uniform within wave
      double acc = 0.0;
      if (o < 10) {
#pragma unroll
        for (int k = 0; k < 4; ++k)
          acc += xd[lane * 4 + k] * (double)cls_w[(lane * 4 + k) * 10 + o];
      } else {
        int oo = o - 10;
#pragma unroll
        for (int k = 0; k < 4; ++k)
          acc += xd[lane * 4 + k] * (double)reg_w[(lane * 4 + k) * 20 + oo];
      }
#pragma unroll
      for (int off = 32; off > 0; off >>= 1) acc += __shfl_down(acc, off);
      if (lane == 0) outv[o] = acc;
    }
  }
  __syncthreads();

  if (t < 5) {
    const int a = t;
    double l0 = outv[2 * a] + (double)cls_b[2 * a];
    double l1 = outv[2 * a + 1] + (double)cls_b[2 * a + 1];
    double sc = 1.0 / (1.0 + exp(l0 - l1));  // == softmax[...,1]
    const int n = p * 5 + a;
    scores[n] = sc;
    double d0 = outv[10 + 4 * a + 0] + (double)reg_b[4 * a + 0];
    double d1 = outv[10 + 4 * a + 1] + (double)reg_b[4 * a + 1];
    double d2 = outv[10 + 4 * a + 2] + (double)reg_b[4 * a + 2];
    double d3 = outv[10 + 4 * a + 3] + (double)reg_b[4 * a + 3];
    double scale = (double)(32 << a);  // 32,64,128,256,512 (ratio=1)
    double wdt = exp(d2) * scale;
    double hgt = exp(d3) * scale;
    double xc = (double)(p % W) + d0;  // FEATURE_STRIDE = 1
    double yc = (double)(p / W) + d1;
    boxes[n * 4 + 0] = xc - 0.5 * wdt;
    boxes[n * 4 + 1] = yc - 0.5 * hgt;
    boxes[n * 4 + 2] = xc + 0.5 * wdt;
    boxes[n * 4 + 3] = yc + 0.5 * hgt;
  }
}

// ---------------------------------------------------------------------------
// Kernel 3: exact stable descending argsort via O(N^2) rank counting.
// Constant-bound inner loop (8x1024 with -1.0 sentinels; scores in (0,1) so
// sentinels never count) -> full unroll window, batched LDS reads.
// ---------------------------------------------------------------------------
__global__ __launch_bounds__(256) void rank_kernel(
    const double* __restrict__ scores, const double* __restrict__ boxes,
    double* __restrict__ bs, double* __restrict__ area) {
  __shared__ double sch[1024];
  const int t = threadIdx.x;
  const int i = blockIdx.x * 256 + t;
  const bool act = i < NBOX;
  const double si = act ? scores[i] : 0.0;
  int cnt = 0;
  for (int base = 0; base < 8192; base += 1024) {
    __syncthreads();
#pragma unroll
    for (int q = 0; q < 4; ++q) {
      int j = base + t * 4 + q;
      sch[t * 4 + q] = (j < NBOX) ? scores[j] : -1.0;
    }
    __syncthreads();
#pragma unroll 16
    for (int jj = 0; jj < 1024; jj += 2) {
      double a0 = sch[jj], a1 = sch[jj + 1];
      int j0 = base + jj;
      cnt += (a0 > si || (a0 == si && j0 < i)) ? 1 : 0;
      cnt += (a1 > si || (a1 == si && (j0 + 1) < i)) ? 1 : 0;
    }
  }
  if (act) {
    double b0 = boxes[i * 4 + 0], b1 = boxes[i * 4 + 1];
    double b2 = boxes[i * 4 + 2], b3 = boxes[i * 4 + 3];
    bs[cnt * 4 + 0] = b0;
    bs[cnt * 4 + 1] = b1;
    bs[cnt * 4 + 2] = b2;
    bs[cnt * 4 + 3] = b3;
    area[cnt] = (b2 - b0) * (b3 - b1);
  }
}

// ---------------------------------------------------------------------------
// Kernel 4a: suppression bit-matrix. Row i, word tj: bit l set iff
// j = tj*64+l has j>i and iou(i,j) >= 0.7. Div-free compare:
// inter >= 0.7*(ai+aj-inter)  (union always > 0; identical decision).
// Only tiles tj >= ti are ever read by the resolver -> early-exit others.
// ---------------------------------------------------------------------------
__global__ __launch_bounds__(256) void iou_matrix_kernel(
    const double* __restrict__ bs, const double* __restrict__ area,
    unsigned long long* __restrict__ supmat) {
  __shared__ double jx1[64], jy1[64], jx2[64], jy2[64], ja[64];
  __shared__ double ix1[64], iy1[64], ix2[64], iy2[64], ia[64];
  const int ti = blockIdx.x / NCH, tj = blockIdx.x % NCH;
  if (tj < ti) return;  // lower triangle never read
  const int t = threadIdx.x, wv = t >> 6, lane = t & 63;
  if (t < 64) {
    int j = tj * 64 + t;
    jx1[t] = bs[j * 4 + 0];
    jy1[t] = bs[j * 4 + 1];
    jx2[t] = bs[j * 4 + 2];
    jy2[t] = bs[j * 4 + 3];
    ja[t] = area[j];
  } else if (t < 128) {
    int l = t - 64;
    int i = ti * 64 + l;
    ix1[l] = bs[i * 4 + 0];
    iy1[l] = bs[i * 4 + 1];
    ix2[l] = bs[i * 4 + 2];
    iy2[l] = bs[i * 4 + 3];
    ia[l] = area[i];
  }
  __syncthreads();
  const double x1 = jx1[lane], y1 = jy1[lane], x2 = jx2[lane], y2 = jy2[lane];
  const double aj = ja[lane];
  const int jglob = tj * 64 + lane;
#pragma unroll 4
  for (int s = 0; s < 16; ++s) {
    const int il = wv * 16 + s;
    const int i = ti * 64 + il;
    const double bx1 = ix1[il], by1 = iy1[il], bx2 = ix2[il], by2 = iy2[il];
    const double ai = ia[il];
    double iw = fmin(x2, bx2) - fmax(x1, bx1);
    iw = iw > 0.0 ? iw : 0.0;
    double ih = fmin(y2, by2) - fmax(y1, by1);
    ih = ih > 0.0 ? ih : 0.0;
    double inter = iw * ih;
    bool sup = (jglob > i) && (inter >= 0.7 * (ai + aj - inter));
    unsigned long long wmask = __ballot(sup ? 1 : 0);
    if (lane == 0) supmat[(size_t)i * ROWW + tj] = wmask;
  }
}

// ---------------------------------------------------------------------------
// Kernel 4b: serial greedy resolution, 1024 threads. Wave0 does the serial
// in-register resolution (diag words prefetched 1 chunk ahead); then ONE
// THREAD PER FUTURE MASK WORD (thread t owns word tc+1+t) pulls the kept
// rows' words — coalesced 1KB bursts, one load-latency per chunk. Early-exit
// at 300 kept (suppression only flows forward).
// ---------------------------------------------------------------------------
__global__ __launch_bounds__(1024) void nms_serial_kernel(
    const double* __restrict__ bs,
    const unsigned long long* __restrict__ supmat,
    float* __restrict__ rois_out) {
  __shared__ unsigned long long mask[NCH];
  __shared__ unsigned long long keptb_sh;
  __shared__ int nk_sh;
  __shared__ int selK[MAXDET];
  const int t = threadIdx.x;
  const int lane = t & 63;
  const int wv = t >> 6;

  if (t < NCH) mask[t] = 0ull;
  if (t == 0) nk_sh = 0;
  __syncthreads();

  unsigned long long wdiag = 0ull;
  if (wv == 0) wdiag = supmat[(size_t)lane * ROWW + 0];

  int nk = 0;
  for (int tc = 0; tc < NCH; ++tc) {
    if (wv == 0) {
      unsigned long long m = mask[tc];   // uniform LDS broadcast
      unsigned long long wcur = wdiag;
      unsigned long long wnext = 0ull;   // prefetch next chunk's diag words
      if (tc + 1 < NCH)
        wnext = supmat[(size_t)((tc + 1) * 64 + lane) * ROWW + (tc + 1)];

      unsigned long long cand = ~m;      // all 64 slots valid (8000=125*64)
      unsigned long long keptbits = 0ull;
      while (cand && nk < MAXDET) {      // uniform serial loop
        int b = __ffsll(cand) - 1;
        unsigned long long bit = 1ull << b;
        keptbits |= bit;
        if (lane == 0) selK[nk] = tc * 64 + b;
        nk++;
        unsigned long long row = __shfl(wcur, b);
        cand &= ~(row | bit);
      }
      wdiag = wnext;
      if (lane == 0) {
        keptb_sh = keptbits;
        nk_sh = nk;
      }
    }
    __syncthreads();

    // Propagate: thread t owns mask word w = tc+1+t.
    unsigned long long kb = keptb_sh;
    nk = nk_sh;  // uniform across all 1024 threads
    const int w = tc + 1 + t;
    if (w < NCH && kb) {
      unsigned long long a = 0ull;
      do {
        int b = __ffsll(kb) - 1;
        kb &= kb - 1;
        a |= supmat[(size_t)(tc * 64 + b) * ROWW + w];
      } while (kb);
      mask[w] |= a;
    }
    __syncthreads();
    if (nk >= MAXDET) break;
  }

  const int NK = nk;  // uniform
  for (int r = t; r < MAXDET; r += 1024) {
    if (r < NK) {
      int p = selK[r];
      rois_out[r * 4 + 0] = (float)bs[p * 4 + 0];
      rois_out[r * 4 + 1] = (float)bs[p * 4 + 1];
      rois_out[r * 4 + 2] = (float)bs[p * 4 + 2];
      rois_out[r * 4 + 3] = (float)bs[p * 4 + 3];
    } else {  // rois = b[sel] * 0 exactly
      rois_out[r * 4 + 0] = 0.f;
      rois_out[r * 4 + 1] = 0.f;
      rois_out[r * 4 + 2] = 0.f;
      rois_out[r * 4 + 3] = 0.f;
    }
  }
}

// ---------------------------------------------------------------------------
// Kernel 5: FC head (fp32; tolerances generous, softmax saturated).
// ---------------------------------------------------------------------------
__global__ __launch_bounds__(256) void rcnn_head_kernel(
    const float* __restrict__ rois, const float* __restrict__ fc1_w,
    const float* __restrict__ fc1_b, const float* __restrict__ clsh_w,
    const float* __restrict__ clsh_b, const float* __restrict__ regh_w,
    const float* __restrict__ regh_b, float* __restrict__ out) {
  __shared__ float red[256 * 8];
  const int r = blockIdx.x, t = threadIdx.x;
  const float r0 = rois[r * 4 + 0], r1 = rois[r * 4 + 1];
  const float r2 = rois[r * 4 + 2], r3 = rois[r * 4 + 3];
  float pc[4] = {0, 0, 0, 0}, pb[4] = {0, 0, 0, 0};
#pragma unroll
  for (int q = 0; q < 4; ++q) {
    int j = t * 4 + q;
    float f = r0 * fc1_w[j] + r1 * fc1_w[1024 + j] + r2 * fc1_w[2048 + j] +
              r3 * fc1_w[3072 + j] + fc1_b[j];
    f = fmaxf(f, 0.f);
#pragma unroll
    for (int c = 0; c < 4; ++c) {
      pc[c] += f * clsh_w[j * 4 + c];
      pb[c] += f * regh_w[j * 4 + c];
    }
  }
#pragma unroll
  for (int u = 0; u < 4; ++u) {
    red[t * 8 + u] = pc[u];
    red[t * 8 + 4 + u] = pb[u];
  }
  __syncthreads();
  for (int s = 128; s > 0; s >>= 1) {
    if (t < s) {
#pragma unroll
      for (int u = 0; u < 8; ++u) red[t * 8 + u] += red[(t + s) * 8 + u];
    }
    __syncthreads();
  }
  if (t == 0) {
    float lg[4];
    float m = -1e30f;
#pragma unroll
    for (int c = 0; c < 4; ++c) {
      lg[c] = red[c] + clsh_b[c];
      m = fmaxf(m, lg[c]);
    }
    float s = 0.f;
#pragma unroll
    for (int c = 0; c < 4; ++c) {
      lg[c] = expf(lg[c] - m);
      s += lg[c];
    }
#pragma unroll
    for (int c = 0; c < 4; ++c) out[r * 4 + c] = lg[c] / s;
#pragma unroll
    for (int k = 0; k < 4; ++k)
      out[1200 + r * 4 + k] = red[4 + k] + regh_b[k];
  }
}

// ---------------------------------------------------------------------------
extern "C" void kernel_launch(void* const* d_in, const int* in_sizes, int n_in,
                              void* d_out, int out_size, void* d_ws,
                              size_t ws_size, hipStream_t stream) {
  const float* feat = (const float*)d_in[0];
  const float* conv_w = (const float*)d_in[1];
  const float* conv_b = (const float*)d_in[2];
  const float* cls_w = (const float*)d_in[3];
  const float* cls_b = (const float*)d_in[4];
  const float* reg_w = (const float*)d_in[5];
  const float* reg_b = (const float*)d_in[6];
  const float* fc1_w = (const float*)d_in[7];
  const float* fc1_b = (const float*)d_in[8];
  const float* clsh_w = (const float*)d_in[9];
  const float* clsh_b = (const float*)d_in[10];
  const float* regh_w = (const float*)d_in[11];
  const float* regh_b = (const float*)d_in[12];
  float* out = (float*)d_out;

  char* w = (char*)d_ws;
  double* xsum = (double*)(w);                 // 1600*256*8   = 3,276,800 B
  double* scores = (double*)(w + 3276800);     // 8000*8       =    64,000 B
  double* boxes = (double*)(w + 3340800);      // 8000*4*8     =   256,000 B
  double* bs = (double*)(w + 3596800);         // 8000*4*8     =   256,000 B
  double* area = (double*)(w + 3852800);       // 8000*8       =    64,000 B
  unsigned long long* supmat =
      (unsigned long long*)(w + 3916800);      // 8000*128*8   = 8,192,000 B

  hipMemsetAsync(xsum, 0, 3276800, stream);
  conv3x3_kernel<<<2560, 512, 0, stream>>>(feat, conv_w, xsum);
  heads_kernel<<<1600, 256, 0, stream>>>(xsum, conv_b, cls_w, cls_b, reg_w,
                                         reg_b, scores, boxes);
  rank_kernel<<<32, 256, 0, stream>>>(scores, boxes, bs, area);
  iou_matrix_kernel<<<NCH * NCH, 256, 0, stream>>>(bs, area, supmat);
  nms_serial_kernel<<<1, 1024, 0, stream>>>(bs, supmat, out + 2400);
  rcnn_head_kernel<<<300, 256, 0, stream>>>(out + 2400, fc1_w, fc1_b, clsh_w,
                                            clsh_b, regh_w, regh_b, out);
}

// Round 8
// 551.783 us; speedup vs baseline: 2.6149x; 1.5314x over previous
//
#include <hip/hip_runtime.h>
#include <math.h>

// ---------------------------------------------------------------------------
// Faster-RCNN head pipeline on gfx950.
// fp64 for everything selection-affecting (matches numpy f64 ordering).
//
// R1: NMS -> iou bit-matrix + 1-wave serial resolve.
// R2: f64 MFMA conv FAILED (f64 C/D layout != bf16 family).
// R3: probe-calibrated D scatter. PASS 893.
// R4: conv retile 2 blocks/CU -> 278us (best conv). PASS 847.
// R5: exact-round grid regressed conv (atomics x2); nms tweaks neutral.
// R6: fused cooperative kernel FAILED (coop launch never ran; plus a
//     poison-read bug in wcrit prefetch past column NCH).
// R7: revert to split dispatches. Conv = byte-exact R4. NMS rebuilt:
//     1024 thr; wave0 resolves with SPECULATIVE crit-word prefetch (the
//     next chunk's column loaded one chunk ahead, reduced via shfl-OR);
//     waves 1-7 concurrently propagate the PREVIOUS chunk's kept rows,
//     <=1 load per thread per chunk (parallel over rows x words) ->
//     one load-latency per chunk instead of a serial chain. Rank
//     parallelized to 256k threads (32 slices/box).
// ---------------------------------------------------------------------------

#define H 40
#define W 40
#define CIN 2048
#define CMID 256
#define NBOX 8000   // 40*40*5
#define NCH 125     // NBOX / 64 chunks
#define ROWW 128    // padded row width (ullong words) of suppression matrix
#define MAXDET 300

typedef double d4 __attribute__((ext_vector_type(4)));

// ---------------------------------------------------------------------------
// Kernel 1: 3x3 SAME conv (2048 -> 256) via v_mfma_f64_16x16x4. (R4 exact)
// Grid 1280 = 20 M-tiles x 2 N-halves x 32 K-splits (64 ch via 2 LDS slabs).
// Block 512 = 8 waves; wave owns 16 outch -> acc = 5 x d4 (40 VGPR).
// D mapping discovered at runtime via probe MFMAs.
// ---------------------------------------------------------------------------
__global__ __launch_bounds__(512, 4) void conv3x3_kernel(
    const float* __restrict__ feat, const float* __restrict__ conv_w,
    double* __restrict__ xsum) {
  __shared__ double patch[4][42][33];  // rows y0-1..y0+2, cols -1..40, 32ch+pad
  const int t = threadIdx.x;
  const int blk = blockIdx.x;
  const int sk = blk & 31;          // K-split: channels c0..c0+63
  const int nh = (blk >> 5) & 1;    // N-half: outch nh*128..+128
  const int mt = blk >> 6;          // M-tile: rows y0, y0+1
  const int y0 = mt * 2;
  const int c0 = sk * 64;

  const int wave = t >> 6, lane = t & 63;
  const int nl = lane & 15;   // A: m-index, B: n-index
  const int kk = lane >> 4;   // k-index within K=4 step
  const int n1 = nh * 128 + wave * 16;

  // --- D-layout self-calibration probes (cost: 2 MFMAs) -------------------
  d4 zero = (d4)0.0;
  double pa1 = (kk == 0) ? 1.0 : 0.0;
  double pb1 = (kk == 0) ? (double)nl : 0.0;
  d4 dcol = __builtin_amdgcn_mfma_f64_16x16x4f64(pa1, pb1, zero, 0, 0, 0);
  double pa2 = (kk == 0) ? (double)nl : 0.0;
  double pb2 = (kk == 0) ? 1.0 : 0.0;
  d4 drow = __builtin_amdgcn_mfma_f64_16x16x4f64(pa2, pb2, zero, 0, 0, 0);

  int apy[5], apx[5];
#pragma unroll
  for (int f = 0; f < 5; ++f) {
    int pos = f * 16 + nl;
    apy[f] = pos / 40;
    apx[f] = pos % 40;
  }

  d4 acc[5];
#pragma unroll
  for (int f = 0; f < 5; ++f) acc[f] = (d4)0.0;

  for (int s2 = 0; s2 < 2; ++s2) {
    const int ch = c0 + s2 * 32;
    if (s2) __syncthreads();  // previous slab fully consumed
    for (int i = t; i < 4 * 42 * 32; i += 512) {
      int c = i & 31;
      int rc = i >> 5;
      int col = rc % 42;
      int row = rc / 42;
      int gy = y0 - 1 + row;
      int gx = col - 1;
      double v = 0.0;
      if (gy >= 0 && gy < H && gx >= 0 && gx < W)
        v = (double)feat[(gy * W + gx) * CIN + ch + c];
      patch[row][col][c] = v;
    }
    __syncthreads();

    for (int tap = 0; tap < 9; ++tap) {
      const int dy = tap / 3, dx = tap % 3;
      const double* ap0 = &patch[apy[0] + dy][apx[0] + dx][kk];
      const double* ap1 = &patch[apy[1] + dy][apx[1] + dx][kk];
      const double* ap2 = &patch[apy[2] + dy][apx[2] + dx][kk];
      const double* ap3 = &patch[apy[3] + dy][apx[3] + dx][kk];
      const double* ap4 = &patch[apy[4] + dy][apx[4] + dx][kk];
      const float* bp = conv_w + ((tap * CIN + ch + kk) * CMID + n1 + nl);
#pragma unroll
      for (int cq = 0; cq < 8; ++cq) {
        const int co = cq * 4;
        double b0 = (double)bp[co * CMID];
        double a0 = ap0[co];
        double a1 = ap1[co];
        double a2 = ap2[co];
        double a3 = ap3[co];
        double a4 = ap4[co];
        acc[0] = __builtin_amdgcn_mfma_f64_16x16x4f64(a0, b0, acc[0], 0, 0, 0);
        acc[1] = __builtin_amdgcn_mfma_f64_16x16x4f64(a1, b0, acc[1], 0, 0, 0);
        acc[2] = __builtin_amdgcn_mfma_f64_16x16x4f64(a2, b0, acc[2], 0, 0, 0);
        acc[3] = __builtin_amdgcn_mfma_f64_16x16x4f64(a3, b0, acc[3], 0, 0, 0);
        acc[4] = __builtin_amdgcn_mfma_f64_16x16x4f64(a4, b0, acc[4], 0, 0, 0);
      }
    }
  }

  // Scatter via PROBED D mapping; combine K-splits with fp64 atomicAdd.
#pragma unroll
  for (int f = 0; f < 5; ++f)
#pragma unroll
    for (int i = 0; i < 4; ++i) {
      int pm = (int)drow[i];
      int pn = (int)dcol[i];
      int pos = f * 16 + pm;
      int py = pos / 40, px = pos % 40;
      int gpos = (y0 + py) * W + px;
      atomicAdd(&xsum[gpos * CMID + n1 + pn], acc[f][i]);
    }
}

// ---------------------------------------------------------------------------
// Kernel 2: bias+ReLU, cls/reg 1x1 convs in fp64, sigmoid score, box decode.
// ---------------------------------------------------------------------------
__global__ __launch_bounds__(256) void heads_kernel(
    const double* __restrict__ xsum, const float* __restrict__ conv_b,
    const float* __restrict__ cls_w, const float* __restrict__ cls_b,
    const float* __restrict__ reg_w, const float* __restrict__ reg_b,
    double* __restrict__ scores, double* __restrict__ boxes) {
  __shared__ double xd[256];
  __shared__ double outv[32];
  const int p = blockIdx.x;
  const int t = threadIdx.x;
  double v = xsum[p * 256 + t] + (double)conv_b[t];
  xd[t] = v > 0.0 ? v : 0.0;
  __syncthreads();

  const int wave = t >> 6, lane = t & 63;
  for (int q = 0; q < 8; ++q) {
    int o = wave * 8 + q;
    if (o < 30) {  // uniform within wave
      double acc = 0.0;
      if (o < 10) {
#pragma unroll
        for (int k = 0; k < 4; ++k)
          acc += xd[lane * 4 + k] * (double)cls_w[(lane * 4 + k) * 10 + o];
      } else {
        int oo = o - 10;
#pragma unroll
        for (int k = 0; k < 4; ++k)
          acc += xd[lane * 4 + k] * (double)reg_w[(lane * 4 + k) * 20 + oo];
      }
#pragma unroll
      for (int off = 32; off > 0; off >>= 1) acc += __shfl_down(acc, off);
      if (lane == 0) outv[o] = acc;
    }
  }
  __syncthreads();

  if (t < 5) {
    const int a = t;
    double l0 = outv[2 * a] + (double)cls_b[2 * a];
    double l1 = outv[2 * a + 1] + (double)cls_b[2 * a + 1];
    double sc = 1.0 / (1.0 + exp(l0 - l1));  // == softmax[...,1]
    const int n = p * 5 + a;
    scores[n] = sc;
    double d0 = outv[10 + 4 * a + 0] + (double)reg_b[4 * a + 0];
    double d1 = outv[10 + 4 * a + 1] + (double)reg_b[4 * a + 1];
    double d2 = outv[10 + 4 * a + 2] + (double)reg_b[4 * a + 2];
    double d3 = outv[10 + 4 * a + 3] + (double)reg_b[4 * a + 3];
    double scale = (double)(32 << a);  // 32,64,128,256,512 (ratio=1)
    double wdt = exp(d2) * scale;
    double hgt = exp(d3) * scale;
    double xc = (double)(p % W) + d0;  // FEATURE_STRIDE = 1
    double yc = (double)(p / W) + d1;
    boxes[n * 4 + 0] = xc - 0.5 * wdt;
    boxes[n * 4 + 1] = yc - 0.5 * hgt;
    boxes[n * 4 + 2] = xc + 0.5 * wdt;
    boxes[n * 4 + 3] = yc + 0.5 * hgt;
  }
}

// ---------------------------------------------------------------------------
// Kernel 3: exact stable descending rank, fully parallel: 32 slices of 250 j
// per box i, shfl-reduce over the 32-subgroup. Grid 1000 x 256.
// ---------------------------------------------------------------------------
__global__ __launch_bounds__(256) void rank_kernel(
    const double* __restrict__ scores, const double* __restrict__ boxes,
    double* __restrict__ bs, double* __restrict__ area) {
  const int gid = blockIdx.x * 256 + threadIdx.x;
  const int i = gid >> 5;
  const int js = gid & 31;
  if (i >= NBOX) return;
  const double si = scores[i];
  int cnt = 0;
  const int j0 = js * 250;
#pragma unroll 5
  for (int j = j0; j < j0 + 250; ++j) {
    double sj = scores[j];
    cnt += (sj > si || (sj == si && j < i)) ? 1 : 0;
  }
#pragma unroll
  for (int off = 16; off > 0; off >>= 1) cnt += __shfl_down(cnt, off, 32);
  if (js == 0) {
    double b0 = boxes[i * 4 + 0], b1 = boxes[i * 4 + 1];
    double b2 = boxes[i * 4 + 2], b3 = boxes[i * 4 + 3];
    bs[cnt * 4 + 0] = b0;
    bs[cnt * 4 + 1] = b1;
    bs[cnt * 4 + 2] = b2;
    bs[cnt * 4 + 3] = b3;
    area[cnt] = (b2 - b0) * (b3 - b1);
  }
}

// ---------------------------------------------------------------------------
// Kernel 4a: suppression bit-matrix (upper-tri tiles only). Div-free:
// inter >= 0.7*union (identical decision; union > 0 always).
// ---------------------------------------------------------------------------
__global__ __launch_bounds__(256) void iou_matrix_kernel(
    const double* __restrict__ bs, const double* __restrict__ area,
    unsigned long long* __restrict__ supmat) {
  __shared__ double jx1[64], jy1[64], jx2[64], jy2[64], ja[64];
  __shared__ double ix1[64], iy1[64], ix2[64], iy2[64], ia[64];
  const int ti = blockIdx.x / NCH, tj = blockIdx.x % NCH;
  if (tj < ti) return;  // lower triangle never read
  const int t = threadIdx.x, wv = t >> 6, lane = t & 63;
  if (t < 64) {
    int j = tj * 64 + t;
    jx1[t] = bs[j * 4 + 0];
    jy1[t] = bs[j * 4 + 1];
    jx2[t] = bs[j * 4 + 2];
    jy2[t] = bs[j * 4 + 3];
    ja[t] = area[j];
  } else if (t < 128) {
    int l = t - 64;
    int i = ti * 64 + l;
    ix1[l] = bs[i * 4 + 0];
    iy1[l] = bs[i * 4 + 1];
    ix2[l] = bs[i * 4 + 2];
    iy2[l] = bs[i * 4 + 3];
    ia[l] = area[i];
  }
  __syncthreads();
  const double x1 = jx1[lane], y1 = jy1[lane], x2 = jx2[lane], y2 = jy2[lane];
  const double aj = ja[lane];
  const int jglob = tj * 64 + lane;
#pragma unroll 4
  for (int s = 0; s < 16; ++s) {
    const int il = wv * 16 + s;
    const int i = ti * 64 + il;
    const double bx1 = ix1[il], by1 = iy1[il], bx2 = ix2[il], by2 = iy2[il];
    const double ai = ia[il];
    double iw = fmin(x2, bx2) - fmax(x1, bx1);
    iw = iw > 0.0 ? iw : 0.0;
    double ih = fmin(y2, by2) - fmax(y1, by1);
    ih = ih > 0.0 ? ih : 0.0;
    double inter = iw * ih;
    bool sup = (jglob > i) && (inter >= 0.7 * (ai + aj - inter));
    unsigned long long wmask = __ballot(sup ? 1 : 0);
    if (lane == 0) supmat[(size_t)i * ROWW + tj] = wmask;
  }
}

// ---------------------------------------------------------------------------
// Kernel 4b: greedy resolution, 1024 threads, 1 barrier/chunk.
// Wave0: resolve chunk tc using mask[tc] | crit, where crit (chunk tc's
// word from chunk tc-1's kept rows) was computed in-register last iter from
// the SPECULATIVELY prefetched column tc of chunk tc-1's rows (shfl-OR over
// kept lanes). Then prefetch chunk tc+1's diag + crit columns (guarded to 0
// past NCH — padding columns are never written!).
// Waves 1-7: propagate chunk tc-1's kept rows into mask words >= tc+1;
// parallel over (rows x words), <=1 load/thread -> one latency per chunk.
// Early-exit at 300 kept (suppression only flows forward).
// ---------------------------------------------------------------------------
__global__ __launch_bounds__(1024) void nms_serial_kernel(
    const double* __restrict__ bs,
    const unsigned long long* __restrict__ supmat,
    float* __restrict__ rois_out) {
  __shared__ unsigned long long mask[NCH];
  __shared__ int selK[MAXDET];
  __shared__ int kbl[2][64];
  __shared__ int kcnt_sh[2];
  __shared__ int nk_sh;
  const int t = threadIdx.x, lane = t & 63;

  for (int q = t; q < NCH; q += 1024) mask[q] = 0ull;
  if (t == 0) {
    kcnt_sh[0] = kcnt_sh[1] = 0;
    nk_sh = 0;
  }
  __syncthreads();

  unsigned long long wdiag = 0ull, wcrit = 0ull, crit = 0ull;
  if (t < 64) {
    wdiag = supmat[(size_t)lane * ROWW + 0];
    wcrit = supmat[(size_t)lane * ROWW + 1];  // NCH > 1
  }
  int nk = 0;
  for (int tc = 0; tc < NCH; ++tc) {
    const int par = tc & 1;
    if (t < 64) {
      unsigned long long m = mask[tc] | crit;
      unsigned long long cand = ~m;
      unsigned long long keptbits = 0ull;
      int cnt = 0;
      while (cand && nk < MAXDET) {  // uniform serial loop
        int b = __ffsll(cand) - 1;
        unsigned long long bit = 1ull << b;
        keptbits |= bit;
        if (lane == 0) {
          selK[nk] = tc * 64 + b;
          kbl[par][cnt] = b;
        }
        cnt++;
        nk++;
        unsigned long long row = __shfl(wdiag, b);
        cand &= ~(row | bit);
      }
      // crit for chunk tc+1: OR of prefetched column tc+1 over kept lanes.
      unsigned long long v = ((keptbits >> lane) & 1ull) ? wcrit : 0ull;
#pragma unroll
      for (int off = 32; off > 0; off >>= 1) v |= __shfl_xor(v, off);
      crit = v;
      // prefetch chunk tc+1's diag and crit columns (guard past NCH).
      if (tc + 1 < NCH) {
        wdiag = supmat[(size_t)((tc + 1) * 64 + lane) * ROWW + (tc + 1)];
        wcrit = (tc + 2 < NCH)
                    ? supmat[(size_t)((tc + 1) * 64 + lane) * ROWW + (tc + 2)]
                    : 0ull;
      }
      if (lane == 0) {
        kcnt_sh[par] = cnt;
        nk_sh = nk;
      }
    } else if (tc > 0) {
      // propagate chunk tc-1's kept rows into words >= tc+1.
      const int pp = par ^ 1;
      const int k = kcnt_sh[pp];
      const int ptc = tc - 1;
      const int w0 = ptc + 2;  // == tc+1
      const int nwords = NCH - w0;
      if (k > 0 && nwords > 0) {
        const int npairs = k * nwords;
        for (int q = t - 64; q < npairs; q += 1024 - 64) {
          int b = kbl[pp][q / nwords];
          int w = w0 + q % nwords;
          unsigned long long r = supmat[(size_t)(ptc * 64 + b) * ROWW + w];
          if (r) {
            unsigned int* mw = (unsigned int*)&mask[w];
            unsigned int lo = (unsigned int)r;
            unsigned int hi = (unsigned int)(r >> 32);
            if (lo) atomicOr(&mw[0], lo);
            if (hi) atomicOr(&mw[1], hi);
          }
        }
      }
    }
    __syncthreads();
    nk = nk_sh;
    if (nk >= MAXDET) break;
  }
  __syncthreads();

  const int NK = nk < MAXDET ? nk : MAXDET;
  for (int r = t; r < MAXDET; r += 1024) {
    if (r < NK) {
      int p = selK[r];
      rois_out[r * 4 + 0] = (float)bs[p * 4 + 0];
      rois_out[r * 4 + 1] = (float)bs[p * 4 + 1];
      rois_out[r * 4 + 2] = (float)bs[p * 4 + 2];
      rois_out[r * 4 + 3] = (float)bs[p * 4 + 3];
    } else {  // rois = b[sel] * 0 exactly
      rois_out[r * 4 + 0] = 0.f;
      rois_out[r * 4 + 1] = 0.f;
      rois_out[r * 4 + 2] = 0.f;
      rois_out[r * 4 + 3] = 0.f;
    }
  }
}

// ---------------------------------------------------------------------------
// Kernel 5: FC head (fp32; tolerances generous, softmax saturated).
// ---------------------------------------------------------------------------
__global__ __launch_bounds__(256) void rcnn_head_kernel(
    const float* __restrict__ rois, const float* __restrict__ fc1_w,
    const float* __restrict__ fc1_b, const float* __restrict__ clsh_w,
    const float* __restrict__ clsh_b, const float* __restrict__ regh_w,
    const float* __restrict__ regh_b, float* __restrict__ out) {
  __shared__ float red[256 * 8];
  const int r = blockIdx.x, t = threadIdx.x;
  const float r0 = rois[r * 4 + 0], r1 = rois[r * 4 + 1];
  const float r2 = rois[r * 4 + 2], r3 = rois[r * 4 + 3];
  float pc[4] = {0, 0, 0, 0}, pb[4] = {0, 0, 0, 0};
#pragma unroll
  for (int q = 0; q < 4; ++q) {
    int j = t * 4 + q;
    float f = r0 * fc1_w[j] + r1 * fc1_w[1024 + j] + r2 * fc1_w[2048 + j] +
              r3 * fc1_w[3072 + j] + fc1_b[j];
    f = fmaxf(f, 0.f);
#pragma unroll
    for (int c = 0; c < 4; ++c) {
      pc[c] += f * clsh_w[j * 4 + c];
      pb[c] += f * regh_w[j * 4 + c];
    }
  }
#pragma unroll
  for (int u = 0; u < 4; ++u) {
    red[t * 8 + u] = pc[u];
    red[t * 8 + 4 + u] = pb[u];
  }
  __syncthreads();
  for (int s = 128; s > 0; s >>= 1) {
    if (t < s) {
#pragma unroll
      for (int u = 0; u < 8; ++u) red[t * 8 + u] += red[(t + s) * 8 + u];
    }
    __syncthreads();
  }
  if (t == 0) {
    float lg[4];
    float m = -1e30f;
#pragma unroll
    for (int c = 0; c < 4; ++c) {
      lg[c] = red[c] + clsh_b[c];
      m = fmaxf(m, lg[c]);
    }
    float s = 0.f;
#pragma unroll
    for (int c = 0; c < 4; ++c) {
      lg[c] = expf(lg[c] - m);
      s += lg[c];
    }
#pragma unroll
    for (int c = 0; c < 4; ++c) out[r * 4 + c] = lg[c] / s;
#pragma unroll
    for (int k = 0; k < 4; ++k)
      out[1200 + r * 4 + k] = red[4 + k] + regh_b[k];
  }
}

// ---------------------------------------------------------------------------
extern "C" void kernel_launch(void* const* d_in, const int* in_sizes, int n_in,
                              void* d_out, int out_size, void* d_ws,
                              size_t ws_size, hipStream_t stream) {
  const float* feat = (const float*)d_in[0];
  const float* conv_w = (const float*)d_in[1];
  const float* conv_b = (const float*)d_in[2];
  const float* cls_w = (const float*)d_in[3];
  const float* cls_b = (const float*)d_in[4];
  const float* reg_w = (const float*)d_in[5];
  const float* reg_b = (const float*)d_in[6];
  const float* fc1_w = (const float*)d_in[7];
  const float* fc1_b = (const float*)d_in[8];
  const float* clsh_w = (const float*)d_in[9];
  const float* clsh_b = (const float*)d_in[10];
  const float* regh_w = (const float*)d_in[11];
  const float* regh_b = (const float*)d_in[12];
  float* out = (float*)d_out;

  char* w = (char*)d_ws;
  double* xsum = (double*)(w);                 // 1600*256*8   = 3,276,800 B
  double* scores = (double*)(w + 3276800);     // 8000*8       =    64,000 B
  double* boxes = (double*)(w + 3340800);      // 8000*4*8     =   256,000 B
  double* bs = (double*)(w + 3596800);         // 8000*4*8     =   256,000 B
  double* area = (double*)(w + 3852800);       // 8000*8       =    64,000 B
  unsigned long long* supmat =
      (unsigned long long*)(w + 3916800);      // 8000*128*8   = 8,192,000 B

  hipMemsetAsync(xsum, 0, 3276800, stream);
  conv3x3_kernel<<<1280, 512, 0, stream>>>(feat, conv_w, xsum);
  heads_kernel<<<1600, 256, 0, stream>>>(xsum, conv_b, cls_w, cls_b, reg_w,
                                         reg_b, scores, boxes);
  rank_kernel<<<1000, 256, 0, stream>>>(scores, boxes, bs, area);
  iou_matrix_kernel<<<NCH * NCH, 256, 0, stream>>>(bs, area, supmat);
  nms_serial_kernel<<<1, 1024, 0, stream>>>(bs, supmat, out + 2400);
  rcnn_head_kernel<<<300, 256, 0, stream>>>(out + 2400, fc1_w, fc1_b, clsh_w,
                                            clsh_b, regh_w, regh_b, out);
}